// Round 8
// baseline (283.794 us; speedup 1.0000x reference)
//
#include <hip/hip_runtime.h>
#include <hip/hip_bf16.h>
#include <math.h>

// Problem constants
#define B 32
#define T 64
#define P 196
#define D 768
#define H 12

typedef __attribute__((ext_vector_type(8))) short short8;
typedef __attribute__((ext_vector_type(4))) float floatx4;

// ---------------- helpers ----------------
__device__ __forceinline__ float wave_sum(float v) {
#pragma unroll
  for (int o = 32; o > 0; o >>= 1) v += __shfl_xor(v, o);
  return v;
}
__device__ __forceinline__ unsigned short f2bf(float x) {
  unsigned u = __float_as_uint(x);
  u += 0x7FFFu + ((u >> 16) & 1u);   // round-to-nearest-even
  return (unsigned short)(u >> 16);
}
__device__ __forceinline__ float bf2f(unsigned short x) {
  return __uint_as_float((unsigned)x << 16);
}
// fast exp: native v_exp_f32 — ~2 VALU instrs vs ~25 for libm expf
__device__ __forceinline__ float fexp(float x) { return __expf(x); }
__device__ __forceinline__ float frcp(float x) { return __builtin_amdgcn_rcpf(x); }
// async global->LDS, 16B per lane; LDS dest = wave-uniform base + lane*16
__device__ __forceinline__ void async_cp16(const unsigned short* g, unsigned short* l) {
  __builtin_amdgcn_global_load_lds(
      (const __attribute__((address_space(1))) unsigned int*)g,
      (__attribute__((address_space(3))) unsigned int*)l, 16, 0, 0);
}
// bijective XCD-chunked remap (m204): each XCD gets one contiguous chunk of tiles
__device__ __forceinline__ int xcd_remap(int orig, int nwg) {
  const int q = nwg >> 3, r = nwg & 7;
  const int x = orig & 7, o = orig >> 3;
  return (x < r ? x * (q + 1) : r * (q + 1) + (x - r) * q) + o;
}

// ---------------- fused prep: weight casts + activation casts + biases + fglob + imask ----
struct WPack {
  const float* src[6];
  unsigned short* dst[6];
};
// blocks [0,3456): transpose6 (z = bid/576, 24x24 tiles of 32x32)
// blocks [3456,9696): cast_rows2
// blocks [9696,9708): build_bias
// blocks [9708,10092): fglob = clip_t @ Wp + bp   (depends only on inputs)
// block 10092: image-adj 3x3 neighbor bitmasks (grid graph: support is 3x3)
__global__ __launch_bounds__(256) void prep_kernel(
    WPack p,
    const float* __restrict__ text, unsigned short* __restrict__ text_bf, int n40,
    const float* __restrict__ img, unsigned short* __restrict__ img_bf, int n41,
    const float* __restrict__ bq, const float* __restrict__ bk,
    const float* __restrict__ bv,
    float* __restrict__ bt, float* __restrict__ bi, float* __restrict__ stok,
    const float* __restrict__ clip_t, const float* __restrict__ Wp,
    const float* __restrict__ bp, float* __restrict__ fglob,
    const int* __restrict__ image_adj, int* __restrict__ imask) {
  const int bid = blockIdx.x;
  if (bid < 3456) {
    __shared__ float tile[32][33];
    const int z = bid / 576, rem = bid % 576;
    const int bx = rem % 24, by = rem / 24;
    const float* W = p.src[z];
    unsigned short* Wt = p.dst[z];
    const int tx = threadIdx.x & 31, ty = threadIdx.x >> 5;  // ty 0..7
    const int n0 = bx * 32, k0 = by * 32;
#pragma unroll
    for (int r = 0; r < 4; ++r)
      tile[ty + 8 * r][tx] = W[(size_t)(k0 + ty + 8 * r) * D + n0 + tx];
    __syncthreads();
#pragma unroll
    for (int r = 0; r < 4; ++r)
      Wt[(size_t)(n0 + ty + 8 * r) * D + k0 + tx] = f2bf(tile[tx][ty + 8 * r]);
  } else if (bid < 9696) {
    int i = (bid - 3456) * 256 + threadIdx.x;
    const float* X;
    unsigned short* Y;
    int idx;
    if (i < n40) { X = text; Y = text_bf; idx = i; }
    else if (i < n40 + n41) { X = img; Y = img_bf; idx = i - n40; }
    else return;
    float4 vv = ((const float4*)X)[idx];
    ushort4 o;
    o.x = f2bf(vv.x); o.y = f2bf(vv.y); o.z = f2bf(vv.z); o.w = f2bf(vv.w);
    ((ushort4*)Y)[idx] = o;
  } else if (bid < 9708) {
    int i = (bid - 9696) * 256 + threadIdx.x;
    if (i < 32) stok[i] = 0.f;
    if (i < 768) { bt[i] = bq[i]; bi[i] = bk[i]; }
    else if (i < 1536) { bt[i] = 0.f; bi[i] = bv[i - 768]; }
    else if (i < 2304) { bi[i] = 0.f; }
  } else if (bid < 10092) {
    // fglob: jt = (bid-9708)%12, b = (bid-9708)/12; 4 indep accumulators (ILP)
    __shared__ float red[4][64];
    const int bid2 = bid - 9708;
    const int jt = bid2 % 12, b = bid2 / 12;
    const int j = threadIdx.x & 63, kc = threadIdx.x >> 6;
    const float* ct = clip_t + b * 512 + kc * 128;
    const float* wp = Wp + (size_t)(kc * 128) * D + jt * 64 + j;
    float s0 = 0.f, s1 = 0.f, s2 = 0.f, s3 = 0.f;
#pragma unroll
    for (int k = 0; k < 128; k += 4) {
      s0 += ct[k]     * wp[(size_t)k * D];
      s1 += ct[k + 1] * wp[(size_t)(k + 1) * D];
      s2 += ct[k + 2] * wp[(size_t)(k + 2) * D];
      s3 += ct[k + 3] * wp[(size_t)(k + 3) * D];
    }
    red[kc][j] = (s0 + s1) + (s2 + s3);
    __syncthreads();
    if (kc == 0)
      fglob[b * D + jt * 64 + j] =
          red[0][j] + red[1][j] + red[2][j] + red[3][j] + bp[jt * 64 + j];
  } else {
    // imask: 9-bit mask of live 3x3 neighbors per node (honors actual adj values)
    const int i = threadIdx.x;
    if (i < P) {
      const int r = i / 14, c = i - r * 14;
      int m = 0;
#pragma unroll
      for (int k = 0; k < 9; ++k) {
        const int nr = r + k / 3 - 1, nc = c + k % 3 - 1;
        if (nr >= 0 && nr < 14 && nc >= 0 && nc < 14 &&
            image_adj[(size_t)i * P + nr * 14 + nc] != 0)
          m |= 1 << k;
      }
      imask[i] = m;
    }
  }
}

// ---------------- bf16 MFMA GEMM body (templated output dtype) ----------------
// Phase-pipelined: phase s: STAGE buf[(s+2)%3] -> vmcnt(4)+lgkmcnt(0) -> ONE
// barrier -> issue ds_reads for frag(s+1) -> 16 register-only MFMAs on frag(s).
// Fragment regs double-buffer; LDS buffers cycle %3; period-6 unroll (rule #20).
// Requires K % 192 == 0 (here K in {384, 768}).
// Swizzle (T2, rule #21): linear LDS dest + inverse-swizzled global source col
// + swizzled read col -> 0 bank conflicts (verified R4).
struct GemmJob {
  const unsigned short* A;   // [M][*] bf16, row stride lda
  const unsigned short* Bt;  // [N][*] bf16, row stride ldb
  const float* bias;
  void* C;                   // fp32 or bf16 per template
  int N, K, lda, ldb, colTiles;
};

template <bool BF16OUT>
__device__ __forceinline__ void gemm_body(const GemmJob& j, int bx, int by, int tid) {
  __shared__ unsigned short As[3][128][32];
  __shared__ unsigned short Bs[3][128][32];
  const int lane = tid & 63;
  const int w = tid >> 6;
  const int quad = lane >> 4;
  const int l15 = lane & 15;
  const int row0 = by * 128;
  const int col0 = bx * 128;
  const int m_off = (w & 1) * 64;
  const int n_off = (w >> 1) * 64;
  const int N = j.N, K = j.K;

  const int srow = 16 * w + (lane >> 2);
  const int scol = (((lane & 3) ^ ((lane >> 3) & 3))) * 8;
  const unsigned short* gA0 = j.A + (size_t)(row0 + srow) * j.lda + scol;
  const unsigned short* gA1 = j.A + (size_t)(row0 + srow + 64) * j.lda + scol;
  const unsigned short* gB0 = j.Bt + (size_t)(col0 + srow) * j.ldb + scol;
  const unsigned short* gB1 = j.Bt + (size_t)(col0 + srow + 64) * j.ldb + scol;

  const int rdc = (quad ^ ((l15 >> 1) & 3)) * 8;

  floatx4 acc[4][4] = {};
  short8 fA[4], fB_[4];   // even-phase fragments
  short8 gA_[4], gB_[4];  // odd-phase fragments

#define STAGE(buf, kk)                                   \
  do {                                                   \
    async_cp16(gA0 + (kk), &As[buf][16 * w][0]);         \
    async_cp16(gA1 + (kk), &As[buf][64 + 16 * w][0]);    \
    async_cp16(gB0 + (kk), &Bs[buf][16 * w][0]);         \
    async_cp16(gB1 + (kk), &Bs[buf][64 + 16 * w][0]);    \
  } while (0)

  auto RD = [&](short8 (&AF)[4], short8 (&BF)[4], int buf) {
#pragma unroll
    for (int i = 0; i < 4; ++i)
      AF[i] = *(const short8*)&As[buf][m_off + 16 * i + l15][rdc];
#pragma unroll
    for (int j2 = 0; j2 < 4; ++j2)
      BF[j2] = *(const short8*)&Bs[buf][n_off + 16 * j2 + l15][rdc];
  };
  auto MM = [&](short8 (&AF)[4], short8 (&BF)[4]) {
#pragma unroll
    for (int i = 0; i < 4; ++i)
#pragma unroll
      for (int j2 = 0; j2 < 4; ++j2)
        acc[i][j2] = __builtin_amdgcn_mfma_f32_16x16x32_bf16(AF[i], BF[j2], acc[i][j2], 0, 0, 0);
  };
  auto PHASE = [&](short8 (&curA)[4], short8 (&curB)[4],
                   short8 (&nxtA)[4], short8 (&nxtB)[4],
                   int stageBuf, int readBuf, int kk) {
    if (kk + 64 < K) {
      STAGE(stageBuf, kk + 64);
      asm volatile("s_waitcnt vmcnt(4) lgkmcnt(0)" ::: "memory");
      __builtin_amdgcn_s_barrier();
      __builtin_amdgcn_sched_barrier(0);
      RD(nxtA, nxtB, readBuf);
    } else if (kk + 32 < K) {
      asm volatile("s_waitcnt vmcnt(0) lgkmcnt(0)" ::: "memory");
      __builtin_amdgcn_s_barrier();
      __builtin_amdgcn_sched_barrier(0);
      RD(nxtA, nxtB, readBuf);
    }
    MM(curA, curB);
  };

  // prologue: stage steps 0,1; wait buf0; read frag(0) into set F
  STAGE(0, 0);
  STAGE(1, 32);
  asm volatile("s_waitcnt vmcnt(4)" ::: "memory");
  __builtin_amdgcn_s_barrier();
  __builtin_amdgcn_sched_barrier(0);
  RD(fA, fB_, 0);

  for (int k0 = 0; k0 < K; k0 += 192) {
    PHASE(fA, fB_, gA_, gB_, 2, 1, k0);        // s%6==0
    PHASE(gA_, gB_, fA, fB_, 0, 2, k0 + 32);   // s%6==1
    PHASE(fA, fB_, gA_, gB_, 1, 0, k0 + 64);   // s%6==2
    PHASE(gA_, gB_, fA, fB_, 2, 1, k0 + 96);   // s%6==3
    PHASE(fA, fB_, gA_, gB_, 0, 2, k0 + 128);  // s%6==4
    PHASE(gA_, gB_, fA, fB_, 1, 0, k0 + 160);  // s%6==5
  }
#undef STAGE

#pragma unroll
  for (int jj = 0; jj < 4; ++jj) {
    const int cg = col0 + n_off + 16 * jj + l15;
    const float bv = j.bias ? j.bias[cg] : 0.0f;
#pragma unroll
    for (int i = 0; i < 4; ++i) {
      const int rbase = row0 + m_off + 16 * i + quad * 4;
#pragma unroll
      for (int r = 0; r < 4; ++r) {
        const float val = acc[i][jj][r] + bv;
        const size_t idx = (size_t)(rbase + r) * N + cg;
        if (BF16OUT) ((unsigned short*)j.C)[idx] = f2bf(val);
        else ((float*)j.C)[idx] = val;
      }
    }
  }
}

// two independent GEMMs in one launch; blockIdx.x < split -> job0 else job1
__global__ __launch_bounds__(256) void gemm_mfma_dual_bf16(GemmJob j0, GemmJob j1,
                                                           int split, int total) {
  const bool first = ((int)blockIdx.x < split);
  const GemmJob& j = first ? j0 : j1;
  const int orig = first ? blockIdx.x : (blockIdx.x - split);
  const int bid = xcd_remap(orig, first ? split : total - split);
  const int bx = bid % j.colTiles;
  const int by = bid / j.colTiles;
  gemm_body<true>(j, bx, by, threadIdx.x);
}

__global__ __launch_bounds__(256) void gemm_mfma_dual_f32(GemmJob j0, GemmJob j1,
                                                          int split, int total) {
  const bool first = ((int)blockIdx.x < split);
  const GemmJob& j = first ? j0 : j1;
  const int orig = first ? blockIdx.x : (blockIdx.x - split);
  const int bid = xcd_remap(orig, first ? split : total - split);
  const int bx = bid % j.colTiles;
  const int by = bid / j.colTiles;
  gemm_body<false>(j, bx, by, threadIdx.x);
}

// ---------------- mid-kernel device bodies (share one 59.6KB LDS arena) --------

// MFMA cross attention, one block per (b,h), 4 waves.
// smem layout: Ks[196][72] (union Ps[4][16][232]) @0 (29952B); VT[64][232] @29952.
__device__ __forceinline__ void attn_body(
    char* smem, int h, int b,
    const unsigned short* __restrict__ qa, const unsigned short* __restrict__ kvw,
    unsigned short* __restrict__ attout) {
  const int tid = threadIdx.x, lane = tid & 63, w = tid >> 6;
  const int quad = lane >> 4, l15 = lane & 15;

  unsigned short (*Ks)[72] = (unsigned short(*)[72])smem;
  unsigned short (*Ps)[16][232] = (unsigned short(*)[16][232])smem;
  unsigned short (*VT)[232] = (unsigned short(*)[232])(smem + 29952);

  // Q fragments first: independent global loads overlap the staging below
  short8 aq[2];
#pragma unroll
  for (int ks = 0; ks < 2; ++ks)
    aq[ks] = *(const short8*)(qa + (size_t)(b * T + 16 * w + l15) * 1536 + h * 64 +
                              32 * ks + quad * 8);

  // K rows: one short8 global load -> one b128 LDS write
  for (int i = tid; i < P * 8; i += 256) {
    const int p = i >> 3, dg = i & 7;
    const short8 k8 =
        *(const short8*)(kvw + (size_t)(b * P + p) * 2304 + h * 64 + dg * 8);
    *(short8*)&Ks[p][dg * 8] = k8;
  }
  // V^T: lane owns column d; coalesced-across-lanes b16 loads -> b128 LDS write.
  {
    const int d = lane;
    const unsigned short* vbase = kvw + (size_t)b * P * 2304 + 768 + h * 64 + d;
    for (int pb = w; pb < 28; pb += 4) {
      short8 v;
#pragma unroll
      for (int z = 0; z < 8; ++z) {
        const int p = pb * 8 + z;
        v[z] = (p < P) ? (short)vbase[(size_t)p * 2304] : (short)0;
      }
      *(short8*)&VT[d][pb * 8] = v;
    }
  }
  __syncthreads();

  floatx4 sc[13];
#pragma unroll
  for (int tile = 0; tile < 13; ++tile) {
    int p = tile * 16 + l15;
    if (p > 195) p = 195;
    short8 bk0 = *(const short8*)&Ks[p][quad * 8];
    short8 bk1 = *(const short8*)&Ks[p][32 + quad * 8];
    floatx4 c = {};
    c = __builtin_amdgcn_mfma_f32_16x16x32_bf16(aq[0], bk0, c, 0, 0, 0);
    c = __builtin_amdgcn_mfma_f32_16x16x32_bf16(aq[1], bk1, c, 0, 0, 0);
    sc[tile] = c;
  }

  float mx[4] = {-3.4e38f, -3.4e38f, -3.4e38f, -3.4e38f};
#pragma unroll
  for (int tile = 0; tile < 13; ++tile)
#pragma unroll
    for (int r = 0; r < 4; ++r) {
      float s = sc[tile][r] * 0.125f;
      if (tile == 12 && l15 >= 4) s = -3.0e38f;
      sc[tile][r] = s;
      mx[r] = fmaxf(mx[r], s);
    }
#pragma unroll
  for (int off = 1; off < 16; off <<= 1)
#pragma unroll
    for (int r = 0; r < 4; ++r) mx[r] = fmaxf(mx[r], __shfl_xor(mx[r], off));

  float sm[4] = {};
#pragma unroll
  for (int tile = 0; tile < 13; ++tile)
#pragma unroll
    for (int r = 0; r < 4; ++r) {
      float e = fexp(sc[tile][r] - mx[r]);   // native v_exp (masked lanes -> 0)
      sc[tile][r] = e;
      sm[r] += e;
    }
#pragma unroll
  for (int off = 1; off < 16; off <<= 1)
#pragma unroll
    for (int r = 0; r < 4; ++r) sm[r] += __shfl_xor(sm[r], off);
  float inv[4];
#pragma unroll
  for (int r = 0; r < 4; ++r) inv[r] = frcp(sm[r]);

  __syncthreads();  // all waves done reading Ks before Ps (same LDS) is written

  // store RAW exp (1/sum deferred to epilogue — it is per-(quad,r) lane-local)
#pragma unroll
  for (int tile = 0; tile < 13; ++tile)
#pragma unroll
    for (int r = 0; r < 4; ++r)
      Ps[w][quad * 4 + r][tile * 16 + l15] = f2bf(sc[tile][r]);
#pragma unroll
  for (int r = 0; r < 4; ++r)
    Ps[w][quad * 4 + r][208 + l15] = 0;

  floatx4 oc[4] = {};
#pragma unroll
  for (int ks = 0; ks < 7; ++ks) {
    short8 pa = *(const short8*)&Ps[w][l15][ks * 32 + quad * 8];
#pragma unroll
    for (int nt = 0; nt < 4; ++nt) {
      short8 bv = *(const short8*)&VT[nt * 16 + l15][ks * 32 + quad * 8];
      oc[nt] = __builtin_amdgcn_mfma_f32_16x16x32_bf16(pa, bv, oc[nt], 0, 0, 0);
    }
  }

#pragma unroll
  for (int nt = 0; nt < 4; ++nt)
#pragma unroll
    for (int r = 0; r < 4; ++r)
      attout[(size_t)(b * T + 16 * w + quad * 4 + r) * 768 + h * 64 + nt * 16 + l15] =
          f2bf(oc[nt][r] * inv[r]);
}

// text GAT, one block per (b,h). smem: VT[64][72]@0, Ps[4][16][72]@9216,
// srcs@18432, dsts@18688, redc[4][64]@18944, asv@19968, adv@20224.
__device__ __forceinline__ void text_gat_body(
    char* smem, int h, int b,
    const unsigned short* __restrict__ Wh, int ldw, const int* __restrict__ adj,
    const float* __restrict__ at, float* __restrict__ tgf) {
  const int tid = threadIdx.x, lane = tid & 63, w = tid >> 6;
  const int quad = lane >> 4, l15 = lane & 15;

  unsigned short (*VT)[72] = (unsigned short(*)[72])smem;
  unsigned short (*Ps)[16][72] = (unsigned short(*)[16][72])(smem + 9216);
  float* srcs = (float*)(smem + 18432);
  float* dsts = (float*)(smem + 18688);
  float (*redc)[64] = (float(*)[64])(smem + 18944);
  float* asv = (float*)(smem + 19968);
  float* adv = (float*)(smem + 20224);

  if (tid < 64) { asv[tid] = at[tid]; adv[tid] = at[64 + tid]; }
  {
    const int f = lane;
    const unsigned short* wbase = Wh + (size_t)(b * T) * ldw + h * 64 + f;
    for (int nb = w; nb < 8; nb += 4) {
      short8 v;
#pragma unroll
      for (int z = 0; z < 8; ++z)
        v[z] = (short)wbase[(size_t)(nb * 8 + z) * ldw];
      *(short8*)&VT[f][nb * 8] = v;
    }
  }
  __syncthreads();

  if (tid < 64) {
    float s = 0.f, dd = 0.f;
#pragma unroll 8
    for (int f = 0; f < 64; ++f) {
      const float wv = bf2f(VT[f][tid]);
      s += wv * asv[f];
      dd += wv * adv[f];
    }
    srcs[tid] = s;
    dsts[tid] = dd;
  }
  __syncthreads();

  const int i = 16 * w + l15;
  const float si = srcs[i];
  const int* ar = adj + (size_t)b * T * T + i * 64;
  float sm = 0.f;
#pragma unroll 8
  for (int jj = 0; jj < 16; ++jj) {
    const int j = 4 * jj + quad;
    float e = si + dsts[j];
    e = (e >= 0.f) ? e : 0.2f * e;
    const float p = (ar[j] != 0) ? fexp(e) : 0.f;
    sm += p;
    Ps[w][l15][j] = f2bf(p);
  }
  sm += __shfl_xor(sm, 16);
  sm += __shfl_xor(sm, 32);
  const float inv = frcp(sm);

  floatx4 oc[4] = {};
#pragma unroll
  for (int ks = 0; ks < 2; ++ks) {
    const short8 pa = *(const short8*)&Ps[w][l15][ks * 32 + quad * 8];
#pragma unroll
    for (int nt = 0; nt < 4; ++nt) {
      const short8 bv = *(const short8*)&VT[nt * 16 + l15][ks * 32 + quad * 8];
      oc[nt] = __builtin_amdgcn_mfma_f32_16x16x32_bf16(pa, bv, oc[nt], 0, 0, 0);
    }
  }

  float accd[4] = {};
#pragma unroll
  for (int r = 0; r < 4; ++r) {
    const float invr = __shfl(inv, quad * 4 + r);  // 1/sum for output row quad*4+r
#pragma unroll
    for (int nt = 0; nt < 4; ++nt) {
      const float hp = oc[nt][r] * invr;
      accd[nt] += (hp > 0.f) ? hp : (fexp(hp) - 1.0f);
    }
  }
#pragma unroll
  for (int nt = 0; nt < 4; ++nt) {
    accd[nt] += __shfl_xor(accd[nt], 16);
    accd[nt] += __shfl_xor(accd[nt], 32);
  }
  if (quad == 0) {
#pragma unroll
    for (int nt = 0; nt < 4; ++nt) redc[w][nt * 16 + l15] = accd[nt];
  }
  __syncthreads();
  if (w == 0) {
    const float tot = redc[0][lane] + redc[1][lane] + redc[2][lane] + redc[3][lane];
    tgf[b * D + h * 64 + lane] = tot * (1.0f / T);
  }
}

// image GAT, SPARSE: the image adjacency is a 14x14 grid graph (<=9 neighbors
// per node, 4.6% dense). Replace the dense 13-tile score+MFMA pipeline with a
// per-node sparse aggregation: wave w owns nodes i == w (mod 4); per node,
// <=9 x {broadcast dst, fexp, per-lane FMA from WhR[j][lane] (128B row read,
// conflict-free)}. No barriers in the main loop, no adj gathers (9-bit masks
// precomputed in prep), no Ps buffer, no dense PV MFMA (50x less FLOP).
// smem: WhR[196][72]@0 (28224), srcs@28224, dsts@29008, asv@29792, adv@30048,
// mloc@30304 (196 ints), redc[4][64]@31088.
__device__ __forceinline__ void image_gat_body(
    char* smem, int h, int b,
    const unsigned short* __restrict__ Wh, int ldw, const float* __restrict__ ai,
    const int* __restrict__ imask, float* __restrict__ igf) {
  const int tid = threadIdx.x, lane = tid & 63, w = tid >> 6;

  unsigned short (*WhR)[72] = (unsigned short(*)[72])smem;
  float* srcs = (float*)(smem + 28224);
  float* dsts = (float*)(smem + 29008);
  float* asv  = (float*)(smem + 29792);
  float* adv  = (float*)(smem + 30048);
  int*   mloc = (int*)(smem + 30304);
  float (*redc)[64] = (float(*)[64])(smem + 31088);

  if (tid < 64) { asv[tid] = ai[tid]; adv[tid] = ai[64 + tid]; }
  if (tid < P) mloc[tid] = imask[tid];
  // stage Wh rows: one short8 global load -> one b128 LDS write
  for (int i = tid; i < P * 8; i += 256) {
    const int p = i >> 3, dg = i & 7;
    *(short8*)&WhR[p][dg * 8] =
        *(const short8*)(Wh + (size_t)(b * P + p) * ldw + h * 64 + dg * 8);
  }
  __syncthreads();

  if (tid < P) {
    float s = 0.f, dd = 0.f;
#pragma unroll 8
    for (int f = 0; f < 64; ++f) {
      const float wv = bf2f(WhR[tid][f]);
      s += wv * asv[f];
      dd += wv * adv[f];
    }
    srcs[tid] = s;
    dsts[tid] = dd;
  }
  __syncthreads();

  float accw = 0.f;   // per-lane f running sum of elu(out) over owned nodes
  for (int i = w; i < P; i += 4) {
    const int m = mloc[i];          // wave-uniform -> uniform branches below
    const float si = srcs[i];
    float psum = 0.f, acc = 0.f;
#pragma unroll
    for (int k = 0; k < 9; ++k) {
      if (m & (1 << k)) {
        const int j = i + (k / 3 - 1) * 14 + (k % 3 - 1);  // in-bounds by mask
        float e = si + dsts[j];
        e = (e >= 0.f) ? e : 0.2f * e;
        const float p = fexp(e);
        psum += p;
        acc += p * bf2f(WhR[j][lane]);
      }
    }
    const float o = acc * frcp(psum);   // self-loop always set -> psum > 0
    accw += (o > 0.f) ? o : (fexp(o) - 1.0f);
  }

  redc[w][lane] = accw;
  __syncthreads();
  if (w == 0)
    igf[b * D + h * 64 + lane] =
        (redc[0][lane] + redc[1][lane] + redc[2][lane] + redc[3][lane]) * (1.0f / P);
}

// ---- merged mid kernel: grid (12, 32, 3); z: 0=attn 1=text_gat 2=image_gat
__global__ __launch_bounds__(256) void mid_kernel(
    const unsigned short* __restrict__ qa_bf, const unsigned short* __restrict__ kvw_bf,
    unsigned short* __restrict__ att_bf,
    const int* __restrict__ text_adj, const float* __restrict__ at,
    float* __restrict__ tgf,
    const unsigned short* __restrict__ whi, int ldw_i,
    const float* __restrict__ ai, const int* __restrict__ imask,
    float* __restrict__ igf) {
  __shared__ __align__(16) char smem[59648];
  const int h = blockIdx.x, b = blockIdx.y, op = blockIdx.z;
  if (op == 0)
    attn_body(smem, h, b, qa_bf, kvw_bf, att_bf);
  else if (op == 1)
    text_gat_body(smem, h, b, qa_bf + 768, 1536, text_adj, at, tgf);
  else
    image_gat_body(smem, h, b, whi, ldw_i, ai, imask, igf);
}

// ---------------- token: grid (12, B). upd = upd0 + upd1 (split-K partials) ----------------
__global__ __launch_bounds__(256) void token_kernel(
    const float* __restrict__ upd0, const float* __restrict__ upd1,
    const float* __restrict__ img,
    float* __restrict__ f_token, float* __restrict__ s_token) {
  const int jt = blockIdx.x, b = blockIdx.y;
  const int l = threadIdx.x & 63, tg = threadIdx.x >> 6;
  const int d = jt * 64 + l;
  float fs = 0.f, ss = 0.f;
#pragma unroll 4
  for (int tt = 0; tt < 16; ++tt) {
    const int t = tg * 16 + tt;
    const size_t idx = (size_t)(b * T + t) * D + d;
    const float u = upd0[idx] + upd1[idx];
    fs += u;
    ss += u * img[(size_t)(b * P + t) * D + d];
  }
  __shared__ float red[4][64];
  __shared__ float sred[4];
  red[tg][l] = fs;
  const float sw = wave_sum(ss);
  if (l == 0) sred[tg] = sw;
  __syncthreads();
  if (tg == 0) {
    f_token[(size_t)b * D + d] =
        (red[0][l] + red[1][l] + red[2][l] + red[3][l]) * (1.0f / T);
    if (threadIdx.x == 0)
      atomicAdd(&s_token[b], (sred[0] + sred[1] + sred[2] + sred[3]) * (1.0f / T));
  }
}

// ---------------- Xc = [f_token; tgf; fglob] @ c1w : grid (6, 96) ----------------
__global__ __launch_bounds__(256) void xc1_kernel(
    const float* __restrict__ ftok, const float* __restrict__ tgf,
    const float* __restrict__ fglob, const float* __restrict__ c1w,
    float* __restrict__ Xc) {
  const int jt = blockIdx.x;
  const int r = blockIdx.y;
  const int b = r & 31, which = r >> 5;
  const float* src = (which == 0 ? ftok : which == 1 ? tgf : fglob) + (size_t)b * D;
  const int j = threadIdx.x & 63, kc = threadIdx.x >> 6;
  const int col = jt * 64 + j;
  const float* cw = c1w + (size_t)(kc * 192) * 384 + col;
  const float* sk = src + kc * 192;
  float s0 = 0.f, s1 = 0.f, s2 = 0.f, s3 = 0.f;
#pragma unroll 12
  for (int k = 0; k < 192; k += 4) {
    s0 += sk[k]     * cw[(size_t)k * 384];
    s1 += sk[k + 1] * cw[(size_t)(k + 1) * 384];
    s2 += sk[k + 2] * cw[(size_t)(k + 2) * 384];
    s3 += sk[k + 3] * cw[(size_t)(k + 3) * 384];
  }
  __shared__ float red[4][64];
  red[kc][j] = (s0 + s1) + (s2 + s3);
  __syncthreads();
  if (kc == 0)
    Xc[(size_t)r * 384 + col] = red[0][j] + red[1][j] + red[2][j] + red[3][j];
}

// ---------------- final fusion kernel: one block per b ----------------
__device__ __forceinline__ float block_sum(float v, float* red4) {
  v = wave_sum(v);
  __syncthreads();
  if ((threadIdx.x & 63) == 0) red4[threadIdx.x >> 6] = v;
  __syncthreads();
  return red4[0] + red4[1] + red4[2] + red4[3];
}

__global__ __launch_bounds__(256) void final_kernel(
    const float* __restrict__ tgf, const float* __restrict__ igf,
    const float* __restrict__ clip_t, const float* __restrict__ clip_i,
    const float* __restrict__ logit_scale, const float* __restrict__ s_token,
    const float* __restrict__ Xc,
    const float* __restrict__ f1w, const float* __restrict__ f1b,
    const float* __restrict__ f2w, const float* __restrict__ f2b,
    const float* __restrict__ c1b,
    const float* __restrict__ c2w, const float* __restrict__ c2b,
    float* __restrict__ out) {
  const int b = blockIdx.x, tid = threadIdx.x;
  __shared__ float red[4];
  __shared__ float sres[4];
  __shared__ float hid[384];

  float d0 = 0.f, d1 = 0.f, d2 = 0.f;
  for (int i = tid; i < D; i += 256) {
    float x = tgf[b * D + i], y = igf[b * D + i];
    d0 += x * y; d1 += x * x; d2 += y * y;
  }
  float dot_ti = block_sum(d0, red);
  float n_t = sqrtf(block_sum(d1, red));
  float n_i = sqrtf(block_sum(d2, red));
  float s_phrase = dot_ti / (fmaxf(n_t, 1e-8f) * fmaxf(n_i, 1e-8f));

  float c0 = 0.f, c1 = 0.f, c2 = 0.f;
  for (int i = tid; i < 512; i += 256) {
    float x = clip_t[b * 512 + i], y = clip_i[b * 512 + i];
    c0 += x * y; c1 += x * x; c2 += y * y;
  }
  float dc = block_sum(c0, red);
  float nt2 = sqrtf(block_sum(c1, red));
  float ni2 = sqrtf(block_sum(c2, red));
  float s_global = expf(logit_scale[0]) * dc / (fmaxf(nt2, 1e-8f) * fmaxf(ni2, 1e-8f));

  if (tid == 0) {
    float s3[3] = { s_token[b], s_phrase, s_global };
    float h1[16];
    for (int j = 0; j < 16; ++j) {
      float a = f1b[j];
      for (int i2 = 0; i2 < 3; ++i2) a += s3[i2] * f1w[i2 * 16 + j];
      h1[j] = 0.5f * a * (1.0f + erff(a * 0.70710678118654752f));
    }
    for (int j = 0; j < 3; ++j) {
      float a = f2b[j];
      for (int i2 = 0; i2 < 16; ++i2) a += h1[i2] * f2w[i2 * 3 + j];
      sres[j] = 1.0f / (1.0f + expf(-a));
    }
  }
  __syncthreads();
  const float w0 = sres[0], w1 = sres[1], w2 = sres[2];

  for (int j = tid; j < 384; j += 256) {
    const float a = w0 * Xc[(size_t)b * 384 + j] +
                    w1 * Xc[(size_t)(32 + b) * 384 + j] +
                    w2 * Xc[(size_t)(64 + b) * 384 + j] + c1b[j];
    hid[j] = fmaxf(a, 0.0f);
  }
  __syncthreads();

  float p0 = 0.f, p1 = 0.f;
  for (int k2 = tid; k2 < 384; k2 += 256) {
    p0 += hid[k2] * c2w[k2 * 2 + 0];
    p1 += hid[k2] * c2w[k2 * 2 + 1];
  }
  p0 = block_sum(p0, red);
  p1 = block_sum(p1, red);
  if (tid == 0) {
    out[b * 2 + 0] = p0 + c2b[0];
    out[b * 2 + 1] = p1 + c2b[1];
  }
}

// ---------------- launch ----------------
extern "C" void kernel_launch(void* const* d_in, const int* in_sizes, int n_in,
                              void* d_out, int out_size, void* d_ws, size_t ws_size,
                              hipStream_t stream) {
  const float* text   = (const float*)d_in[0];
  const float* img    = (const float*)d_in[1];
  const float* clip_t = (const float*)d_in[2];
  const float* clip_i = (const float*)d_in[3];
  const float* lscale = (const float*)d_in[4];
  const float* wq = (const float*)d_in[5];
  const float* bq = (const float*)d_in[6];
  const float* wk = (const float*)d_in[7];
  const float* bk = (const float*)d_in[8];
  const float* wv = (const float*)d_in[9];
  const float* bv = (const float*)d_in[10];
  const float* wo = (const float*)d_in[11];
  const float* bo = (const float*)d_in[12];
  const float* Wt = (const float*)d_in[13];
  const float* at = (const float*)d_in[14];
  const float* Wi = (const float*)d_in[15];
  const float* ai = (const float*)d_in[16];
  const float* Wp = (const float*)d_in[17];
  const float* bp = (const float*)d_in[18];
  const float* f1w = (const float*)d_in[19];
  const float* f1b = (const float*)d_in[20];
  const float* f2w = (const float*)d_in[21];
  const float* f2b = (const float*)d_in[22];
  const float* c1w = (const float*)d_in[23];
  const float* c1b = (const float*)d_in[24];
  const float* c2w = (const float*)d_in[25];
  const float* c2b = (const float*)d_in[26];
  const int* text_adj  = (const int*)d_in[27];
  const int* image_adj = (const int*)d_in[28];
  float* out = (float*)d_out;

  const size_t nTD = (size_t)B * T * D;   // 1,572,864
  const size_t nPD = (size_t)B * P * D;   // 4,816,896
  const size_t nWW = (size_t)D * D;       // 589,824

  // ---- workspace layout (no aliasing) ----
  float* fbuf = (float*)d_ws;
  size_t o = 0;
  float* upd0    = fbuf + o; o += nTD;     // wo GEMM split-K partial 0 (with bias)
  float* upd1    = fbuf + o; o += nTD;     // partial 1
  float* ftok    = fbuf + o; o += (size_t)B * D;
  float* stok    = fbuf + o; o += 32;
  float* tgf     = fbuf + o; o += (size_t)B * D;
  float* igf     = fbuf + o; o += (size_t)B * D;
  float* fglob   = fbuf + o; o += (size_t)B * D;
  float* bcat_t  = fbuf + o; o += 1536;
  float* bcat_i3 = fbuf + o; o += 2304;
  float* Xc      = fbuf + o; o += (size_t)96 * 384;
  int*   imask   = (int*)(fbuf + o); o += 256;   // 196 used, padded
  unsigned short* sbuf = (unsigned short*)(fbuf + o);
  size_t so = 0;
  unsigned short* kvw_bf    = sbuf + so; so += 3 * nPD;  // [B*P][2304] bf16: k|v|Wh_i
  unsigned short* qa_bf     = sbuf + so; so += 2 * nTD;  // [B*T][1536] bf16: q|Wh_t
  unsigned short* text_bf   = sbuf + so; so += nTD;
  unsigned short* img_bf    = sbuf + so; so += nPD;
  unsigned short* att_bf    = sbuf + so; so += nTD;
  unsigned short* wcat_txt  = sbuf + so; so += 2 * nWW;  // wq^T | Wt^T
  unsigned short* wcat_img3 = sbuf + so; so += 3 * nWW;  // wk^T | wv^T | Wi^T
  unsigned short* wo_t      = sbuf + so; so += nWW;

  // ---- fused prep: weight casts + biases + activation casts + fglob + imask ----
  WPack wp;
  wp.src[0] = wq; wp.dst[0] = wcat_txt;
  wp.src[1] = Wt; wp.dst[1] = wcat_txt + nWW;
  wp.src[2] = wk; wp.dst[2] = wcat_img3;
  wp.src[3] = wv; wp.dst[3] = wcat_img3 + nWW;
  wp.src[4] = Wi; wp.dst[4] = wcat_img3 + 2 * nWW;
  wp.src[5] = wo; wp.dst[5] = wo_t;
  {
    const int n40 = (int)(nTD / 4), n41 = (int)(nPD / 4);
    prep_kernel<<<10093, 256, 0, stream>>>(wp, text, text_bf, n40, img, img_bf, n41,
                                           bq, bk, bv, bcat_t, bcat_i3, stok,
                                           clip_t, Wp, bp, fglob, image_adj, imask);
  }

  const int MT = B * T;   // 2048
  const int MP = B * P;   // 6272

  // ---- fused projections (bf16 C output): one dual launch ----
  GemmJob jimg;  // kvw_bf = img @ [wk|wv|Wi] + [bk,bv,0]
  jimg.A = img_bf; jimg.Bt = wcat_img3; jimg.bias = bcat_i3; jimg.C = kvw_bf;
  jimg.N = 2304; jimg.K = D; jimg.lda = D; jimg.ldb = D; jimg.colTiles = 2304 / 128;
  GemmJob jtxt;  // qa_bf = text @ [wq|Wt] + [bq,0]
  jtxt.A = text_bf; jtxt.Bt = wcat_txt; jtxt.bias = bcat_t; jtxt.C = qa_bf;
  jtxt.N = 1536; jtxt.K = D; jtxt.lda = D; jtxt.ldb = D; jtxt.colTiles = 1536 / 128;
  const int splitBlocks = (2304 / 128) * (MP / 128);                // 882
  const int totalBlocks = splitBlocks + (1536 / 128) * (MT / 128);  // 882 + 192
  gemm_mfma_dual_bf16<<<totalBlocks, 256, 0, stream>>>(jimg, jtxt, splitBlocks, totalBlocks);

  // ---- merged mid: attn + text GAT + sparse image GAT, one launch ----
  const unsigned short* whi_bf = kvw_bf + 1536;
  mid_kernel<<<dim3(H, B, 3), 256, 0, stream>>>(
      qa_bf, kvw_bf, att_bf,
      text_adj, at, tgf,
      whi_bf, 2304, ai, imask, igf);

  // ---- wo GEMM split-K x2 in one dual launch (192 blocks) ----
  GemmJob jwo0;  // upd0 = att[:, :384] @ wo_t[:, :384]^T + bo
  jwo0.A = att_bf; jwo0.Bt = wo_t; jwo0.bias = bo; jwo0.C = upd0;
  jwo0.N = D; jwo0.K = 384; jwo0.lda = D; jwo0.ldb = D; jwo0.colTiles = D / 128;
  GemmJob jwo1;  // upd1 = att[:, 384:] @ wo_t[:, 384:]^T
  jwo1.A = att_bf + 384; jwo1.Bt = wo_t + 384; jwo1.bias = nullptr; jwo1.C = upd1;
  jwo1.N = D; jwo1.K = 384; jwo1.lda = D; jwo1.ldb = D; jwo1.colTiles = D / 128;
  const int woHalf = (D / 128) * (MT / 128);  // 96
  gemm_mfma_dual_f32<<<2 * woHalf, 256, 0, stream>>>(jwo0, jwo1, woHalf, 2 * woHalf);

  token_kernel<<<dim3(12, B), 256, 0, stream>>>(upd0, upd1, img, ftok, stok);
  xc1_kernel<<<dim3(6, 96), 256, 0, stream>>>(ftok, tgf, fglob, c1w, Xc);
  final_kernel<<<B, 256, 0, stream>>>(tgf, igf, clip_t, clip_i, lscale, stok, Xc,
                                      f1w, f1b, f2w, f2b, c1b, c2w, c2b, out);
}

// Round 9
// 263.004 us; speedup vs baseline: 1.0790x; 1.0790x over previous
//
#include <hip/hip_runtime.h>
#include <hip/hip_bf16.h>
#include <math.h>

// Problem constants
#define B 32
#define T 64
#define P 196
#define D 768
#define H 12

typedef __attribute__((ext_vector_type(8))) short short8;
typedef __attribute__((ext_vector_type(4))) float floatx4;

// ---------------- helpers ----------------
__device__ __forceinline__ float wave_sum(float v) {
#pragma unroll
  for (int o = 32; o > 0; o >>= 1) v += __shfl_xor(v, o);
  return v;
}
__device__ __forceinline__ unsigned short f2bf(float x) {
  unsigned u = __float_as_uint(x);
  u += 0x7FFFu + ((u >> 16) & 1u);   // round-to-nearest-even
  return (unsigned short)(u >> 16);
}
__device__ __forceinline__ float bf2f(unsigned short x) {
  return __uint_as_float((unsigned)x << 16);
}
// fast exp: native v_exp_f32 — ~2 VALU instrs vs ~25 for libm expf
__device__ __forceinline__ float fexp(float x) { return __expf(x); }
__device__ __forceinline__ float frcp(float x) { return __builtin_amdgcn_rcpf(x); }
// async global->LDS, 16B per lane; LDS dest = wave-uniform base + lane*16
__device__ __forceinline__ void async_cp16(const unsigned short* g, unsigned short* l) {
  __builtin_amdgcn_global_load_lds(
      (const __attribute__((address_space(1))) unsigned int*)g,
      (__attribute__((address_space(3))) unsigned int*)l, 16, 0, 0);
}
// bijective XCD-chunked remap (m204): each XCD gets one contiguous chunk of tiles
__device__ __forceinline__ int xcd_remap(int orig, int nwg) {
  const int q = nwg >> 3, r = nwg & 7;
  const int x = orig & 7, o = orig >> 3;
  return (x < r ? x * (q + 1) : r * (q + 1) + (x - r) * q) + o;
}

// ---------------- fused prep: 6x weight cast-transpose + activation casts + biases ----
struct WPack {
  const float* src[6];
  unsigned short* dst[6];
};
// blocks [0,3456): transpose6 (z = bid/576, 24x24 tiles of 32x32)
// blocks [3456,9696): cast_rows2
// blocks [9696,9708): build_bias
__global__ __launch_bounds__(256) void prep_kernel(
    WPack p,
    const float* __restrict__ text, unsigned short* __restrict__ text_bf, int n40,
    const float* __restrict__ img, unsigned short* __restrict__ img_bf, int n41,
    const float* __restrict__ bq, const float* __restrict__ bk,
    const float* __restrict__ bv,
    float* __restrict__ bt, float* __restrict__ bi, float* __restrict__ stok) {
  const int bid = blockIdx.x;
  if (bid < 3456) {
    __shared__ float tile[32][33];
    const int z = bid / 576, rem = bid % 576;
    const int bx = rem % 24, by = rem / 24;
    const float* W = p.src[z];
    unsigned short* Wt = p.dst[z];
    const int tx = threadIdx.x & 31, ty = threadIdx.x >> 5;  // ty 0..7
    const int n0 = bx * 32, k0 = by * 32;
#pragma unroll
    for (int r = 0; r < 4; ++r)
      tile[ty + 8 * r][tx] = W[(size_t)(k0 + ty + 8 * r) * D + n0 + tx];
    __syncthreads();
#pragma unroll
    for (int r = 0; r < 4; ++r)
      Wt[(size_t)(n0 + ty + 8 * r) * D + k0 + tx] = f2bf(tile[tx][ty + 8 * r]);
  } else if (bid < 9696) {
    int i = (bid - 3456) * 256 + threadIdx.x;
    const float* X;
    unsigned short* Y;
    int idx;
    if (i < n40) { X = text; Y = text_bf; idx = i; }
    else if (i < n40 + n41) { X = img; Y = img_bf; idx = i - n40; }
    else return;
    float4 vv = ((const float4*)X)[idx];
    ushort4 o;
    o.x = f2bf(vv.x); o.y = f2bf(vv.y); o.z = f2bf(vv.z); o.w = f2bf(vv.w);
    ((ushort4*)Y)[idx] = o;
  } else {
    int i = (bid - 9696) * 256 + threadIdx.x;
    if (i < 32) stok[i] = 0.f;
    if (i < 768) { bt[i] = bq[i]; bi[i] = bk[i]; }
    else if (i < 1536) { bt[i] = 0.f; bi[i] = bv[i - 768]; }
    else if (i < 2304) { bi[i] = 0.f; }
  }
}

// ---------------- bf16 MFMA GEMM body (LDS arena passed in) ----------------
// Phase-pipelined: phase s: STAGE buf[(s+2)%3] -> vmcnt(4)+lgkmcnt(0) -> ONE
// barrier -> issue ds_reads for frag(s+1) -> 16 register-only MFMAs on frag(s).
// Fragment regs double-buffer; LDS buffers cycle %3; period-6 unroll (rule #20).
// Requires K % 192 == 0 (here K in {384, 768}). Needs 49152B of LDS arena.
// Swizzle (T2, rule #21): linear LDS dest + inverse-swizzled global source col
// + swizzled read col -> 0 bank conflicts (verified R4).
struct GemmJob {
  const unsigned short* A;   // [M][*] bf16, row stride lda
  const unsigned short* Bt;  // [N][*] bf16, row stride ldb
  const float* bias;
  void* C;                   // fp32 or bf16 per template
  int N, K, lda, ldb, colTiles;
};

template <bool BF16OUT>
__device__ __forceinline__ void gemm_body(const GemmJob& j, int bx, int by, int tid,
                                          char* smem) {
  unsigned short (*As)[128][32] = (unsigned short(*)[128][32])smem;
  unsigned short (*Bs)[128][32] = (unsigned short(*)[128][32])(smem + 24576);
  const int lane = tid & 63;
  const int w = tid >> 6;
  const int quad = lane >> 4;
  const int l15 = lane & 15;
  const int row0 = by * 128;
  const int col0 = bx * 128;
  const int m_off = (w & 1) * 64;
  const int n_off = (w >> 1) * 64;
  const int N = j.N, K = j.K;

  const int srow = 16 * w + (lane >> 2);
  const int scol = (((lane & 3) ^ ((lane >> 3) & 3))) * 8;
  const unsigned short* gA0 = j.A + (size_t)(row0 + srow) * j.lda + scol;
  const unsigned short* gA1 = j.A + (size_t)(row0 + srow + 64) * j.lda + scol;
  const unsigned short* gB0 = j.Bt + (size_t)(col0 + srow) * j.ldb + scol;
  const unsigned short* gB1 = j.Bt + (size_t)(col0 + srow + 64) * j.ldb + scol;

  const int rdc = (quad ^ ((l15 >> 1) & 3)) * 8;

  floatx4 acc[4][4] = {};
  short8 fA[4], fB_[4];   // even-phase fragments
  short8 gA_[4], gB_[4];  // odd-phase fragments

#define STAGE(buf, kk)                                   \
  do {                                                   \
    async_cp16(gA0 + (kk), &As[buf][16 * w][0]);         \
    async_cp16(gA1 + (kk), &As[buf][64 + 16 * w][0]);    \
    async_cp16(gB0 + (kk), &Bs[buf][16 * w][0]);         \
    async_cp16(gB1 + (kk), &Bs[buf][64 + 16 * w][0]);    \
  } while (0)

  auto RD = [&](short8 (&AF)[4], short8 (&BF)[4], int buf) {
#pragma unroll
    for (int i = 0; i < 4; ++i)
      AF[i] = *(const short8*)&As[buf][m_off + 16 * i + l15][rdc];
#pragma unroll
    for (int j2 = 0; j2 < 4; ++j2)
      BF[j2] = *(const short8*)&Bs[buf][n_off + 16 * j2 + l15][rdc];
  };
  auto MM = [&](short8 (&AF)[4], short8 (&BF)[4]) {
#pragma unroll
    for (int i = 0; i < 4; ++i)
#pragma unroll
      for (int j2 = 0; j2 < 4; ++j2)
        acc[i][j2] = __builtin_amdgcn_mfma_f32_16x16x32_bf16(AF[i], BF[j2], acc[i][j2], 0, 0, 0);
  };
  auto PHASE = [&](short8 (&curA)[4], short8 (&curB)[4],
                   short8 (&nxtA)[4], short8 (&nxtB)[4],
                   int stageBuf, int readBuf, int kk) {
    if (kk + 64 < K) {
      STAGE(stageBuf, kk + 64);
      asm volatile("s_waitcnt vmcnt(4) lgkmcnt(0)" ::: "memory");
      __builtin_amdgcn_s_barrier();
      __builtin_amdgcn_sched_barrier(0);
      RD(nxtA, nxtB, readBuf);
    } else if (kk + 32 < K) {
      asm volatile("s_waitcnt vmcnt(0) lgkmcnt(0)" ::: "memory");
      __builtin_amdgcn_s_barrier();
      __builtin_amdgcn_sched_barrier(0);
      RD(nxtA, nxtB, readBuf);
    }
    MM(curA, curB);
  };

  // prologue: stage steps 0,1; wait buf0; read frag(0) into set F
  STAGE(0, 0);
  STAGE(1, 32);
  asm volatile("s_waitcnt vmcnt(4)" ::: "memory");
  __builtin_amdgcn_s_barrier();
  __builtin_amdgcn_sched_barrier(0);
  RD(fA, fB_, 0);

  for (int k0 = 0; k0 < K; k0 += 192) {
    PHASE(fA, fB_, gA_, gB_, 2, 1, k0);        // s%6==0
    PHASE(gA_, gB_, fA, fB_, 0, 2, k0 + 32);   // s%6==1
    PHASE(fA, fB_, gA_, gB_, 1, 0, k0 + 64);   // s%6==2
    PHASE(gA_, gB_, fA, fB_, 2, 1, k0 + 96);   // s%6==3
    PHASE(fA, fB_, gA_, gB_, 0, 2, k0 + 128);  // s%6==4
    PHASE(gA_, gB_, fA, fB_, 1, 0, k0 + 160);  // s%6==5
  }
#undef STAGE

#pragma unroll
  for (int jj = 0; jj < 4; ++jj) {
    const int cg = col0 + n_off + 16 * jj + l15;
    const float bv = j.bias ? j.bias[cg] : 0.0f;
#pragma unroll
    for (int i = 0; i < 4; ++i) {
      const int rbase = row0 + m_off + 16 * i + quad * 4;
#pragma unroll
      for (int r = 0; r < 4; ++r) {
        const float val = acc[i][jj][r] + bv;
        const size_t idx = (size_t)(rbase + r) * N + cg;
        if (BF16OUT) ((unsigned short*)j.C)[idx] = f2bf(val);
        else ((float*)j.C)[idx] = val;
      }
    }
  }
}

// two independent GEMMs in one launch; blockIdx.x < split -> job0 else job1
__global__ __launch_bounds__(256) void gemm_mfma_dual_bf16(GemmJob j0, GemmJob j1,
                                                           int split, int total) {
  __shared__ __align__(16) char gsmem[49152];
  const bool first = ((int)blockIdx.x < split);
  const GemmJob& j = first ? j0 : j1;
  const int orig = first ? blockIdx.x : (blockIdx.x - split);
  const int bid = xcd_remap(orig, first ? split : total - split);
  const int bx = bid % j.colTiles;
  const int by = bid / j.colTiles;
  gemm_body<true>(j, bx, by, threadIdx.x, gsmem);
}

// ---------------- device bodies (share LDS arenas) --------

// MFMA cross attention, one block per (b,h), 4 waves.
// smem layout: Ks[196][72] (union Ps[4][16][232]) @0 (29952B); VT[64][232] @29952.
__device__ __forceinline__ void attn_body(
    char* smem, int h, int b,
    const unsigned short* __restrict__ qa, const unsigned short* __restrict__ kvw,
    unsigned short* __restrict__ attout) {
  const int tid = threadIdx.x, lane = tid & 63, w = tid >> 6;
  const int quad = lane >> 4, l15 = lane & 15;

  unsigned short (*Ks)[72] = (unsigned short(*)[72])smem;
  unsigned short (*Ps)[16][232] = (unsigned short(*)[16][232])smem;
  unsigned short (*VT)[232] = (unsigned short(*)[232])(smem + 29952);

  // Q fragments first: independent global loads overlap the staging below
  short8 aq[2];
#pragma unroll
  for (int ks = 0; ks < 2; ++ks)
    aq[ks] = *(const short8*)(qa + (size_t)(b * T + 16 * w + l15) * 1536 + h * 64 +
                              32 * ks + quad * 8);

  // K rows: one short8 global load -> one b128 LDS write
  for (int i = tid; i < P * 8; i += 256) {
    const int p = i >> 3, dg = i & 7;
    const short8 k8 =
        *(const short8*)(kvw + (size_t)(b * P + p) * 2304 + h * 64 + dg * 8);
    *(short8*)&Ks[p][dg * 8] = k8;
  }
  // V^T: lane owns column d; coalesced-across-lanes b16 loads -> b128 LDS write.
  {
    const int d = lane;
    const unsigned short* vbase = kvw + (size_t)b * P * 2304 + 768 + h * 64 + d;
    for (int pb = w; pb < 28; pb += 4) {
      short8 v;
#pragma unroll
      for (int z = 0; z < 8; ++z) {
        const int p = pb * 8 + z;
        v[z] = (p < P) ? (short)vbase[(size_t)p * 2304] : (short)0;
      }
      *(short8*)&VT[d][pb * 8] = v;
    }
  }
  __syncthreads();

  floatx4 sc[13];
#pragma unroll
  for (int tile = 0; tile < 13; ++tile) {
    int p = tile * 16 + l15;
    if (p > 195) p = 195;
    short8 bk0 = *(const short8*)&Ks[p][quad * 8];
    short8 bk1 = *(const short8*)&Ks[p][32 + quad * 8];
    floatx4 c = {};
    c = __builtin_amdgcn_mfma_f32_16x16x32_bf16(aq[0], bk0, c, 0, 0, 0);
    c = __builtin_amdgcn_mfma_f32_16x16x32_bf16(aq[1], bk1, c, 0, 0, 0);
    sc[tile] = c;
  }

  float mx[4] = {-3.4e38f, -3.4e38f, -3.4e38f, -3.4e38f};
#pragma unroll
  for (int tile = 0; tile < 13; ++tile)
#pragma unroll
    for (int r = 0; r < 4; ++r) {
      float s = sc[tile][r] * 0.125f;
      if (tile == 12 && l15 >= 4) s = -3.0e38f;
      sc[tile][r] = s;
      mx[r] = fmaxf(mx[r], s);
    }
#pragma unroll
  for (int off = 1; off < 16; off <<= 1)
#pragma unroll
    for (int r = 0; r < 4; ++r) mx[r] = fmaxf(mx[r], __shfl_xor(mx[r], off));

  float sm[4] = {};
#pragma unroll
  for (int tile = 0; tile < 13; ++tile)
#pragma unroll
    for (int r = 0; r < 4; ++r) {
      float e = fexp(sc[tile][r] - mx[r]);   // native v_exp (masked lanes -> 0)
      sc[tile][r] = e;
      sm[r] += e;
    }
#pragma unroll
  for (int off = 1; off < 16; off <<= 1)
#pragma unroll
    for (int r = 0; r < 4; ++r) sm[r] += __shfl_xor(sm[r], off);
  float inv[4];
#pragma unroll
  for (int r = 0; r < 4; ++r) inv[r] = frcp(sm[r]);

  __syncthreads();  // all waves done reading Ks before Ps (same LDS) is written

  // store RAW exp (1/sum deferred to epilogue — it is per-(quad,r) lane-local)
#pragma unroll
  for (int tile = 0; tile < 13; ++tile)
#pragma unroll
    for (int r = 0; r < 4; ++r)
      Ps[w][quad * 4 + r][tile * 16 + l15] = f2bf(sc[tile][r]);
#pragma unroll
  for (int r = 0; r < 4; ++r)
    Ps[w][quad * 4 + r][208 + l15] = 0;

  floatx4 oc[4] = {};
#pragma unroll
  for (int ks = 0; ks < 7; ++ks) {
    short8 pa = *(const short8*)&Ps[w][l15][ks * 32 + quad * 8];
#pragma unroll
    for (int nt = 0; nt < 4; ++nt) {
      short8 bv = *(const short8*)&VT[nt * 16 + l15][ks * 32 + quad * 8];
      oc[nt] = __builtin_amdgcn_mfma_f32_16x16x32_bf16(pa, bv, oc[nt], 0, 0, 0);
    }
  }

#pragma unroll
  for (int nt = 0; nt < 4; ++nt)
#pragma unroll
    for (int r = 0; r < 4; ++r)
      attout[(size_t)(b * T + 16 * w + quad * 4 + r) * 768 + h * 64 + nt * 16 + l15] =
          f2bf(oc[nt][r] * inv[r]);
}

// standalone attn kernel: grid (12, 32)
__global__ __launch_bounds__(256) void attn_kernel(
    const unsigned short* __restrict__ qa_bf, const unsigned short* __restrict__ kvw_bf,
    unsigned short* __restrict__ att_bf) {
  __shared__ __align__(16) char smem[59648];
  attn_body(smem, blockIdx.x, blockIdx.y, qa_bf, kvw_bf, att_bf);
}

// text GAT, one block per (b,h). smem: VT[64][72]@0, Ps[4][16][72]@9216,
// srcs@18432, dsts@18688, redc[4][64]@18944, asv@19968, adv@20224. (<=49152)
__device__ __forceinline__ void text_gat_body(
    char* smem, int h, int b,
    const unsigned short* __restrict__ Wh, int ldw, const int* __restrict__ adj,
    const float* __restrict__ at, float* __restrict__ tgf) {
  const int tid = threadIdx.x, lane = tid & 63, w = tid >> 6;
  const int quad = lane >> 4, l15 = lane & 15;

  unsigned short (*VT)[72] = (unsigned short(*)[72])smem;
  unsigned short (*Ps)[16][72] = (unsigned short(*)[16][72])(smem + 9216);
  float* srcs = (float*)(smem + 18432);
  float* dsts = (float*)(smem + 18688);
  float (*redc)[64] = (float(*)[64])(smem + 18944);
  float* asv = (float*)(smem + 19968);
  float* adv = (float*)(smem + 20224);

  if (tid < 64) { asv[tid] = at[tid]; adv[tid] = at[64 + tid]; }
  {
    const int f = lane;
    const unsigned short* wbase = Wh + (size_t)(b * T) * ldw + h * 64 + f;
    for (int nb = w; nb < 8; nb += 4) {
      short8 v;
#pragma unroll
      for (int z = 0; z < 8; ++z)
        v[z] = (short)wbase[(size_t)(nb * 8 + z) * ldw];
      *(short8*)&VT[f][nb * 8] = v;
    }
  }
  __syncthreads();

  if (tid < 64) {
    float s = 0.f, dd = 0.f;
#pragma unroll 8
    for (int f = 0; f < 64; ++f) {
      const float wv = bf2f(VT[f][tid]);
      s += wv * asv[f];
      dd += wv * adv[f];
    }
    srcs[tid] = s;
    dsts[tid] = dd;
  }
  __syncthreads();

  const int i = 16 * w + l15;
  const float si = srcs[i];
  const int* ar = adj + (size_t)b * T * T + i * 64;
  float sm = 0.f;
#pragma unroll 8
  for (int jj = 0; jj < 16; ++jj) {
    const int j = 4 * jj + quad;
    float e = si + dsts[j];
    e = (e >= 0.f) ? e : 0.2f * e;
    const float p = (ar[j] != 0) ? fexp(e) : 0.f;
    sm += p;
    Ps[w][l15][j] = f2bf(p);
  }
  sm += __shfl_xor(sm, 16);
  sm += __shfl_xor(sm, 32);
  const float inv = frcp(sm);

  floatx4 oc[4] = {};
#pragma unroll
  for (int ks = 0; ks < 2; ++ks) {
    const short8 pa = *(const short8*)&Ps[w][l15][ks * 32 + quad * 8];
#pragma unroll
    for (int nt = 0; nt < 4; ++nt) {
      const short8 bv = *(const short8*)&VT[nt * 16 + l15][ks * 32 + quad * 8];
      oc[nt] = __builtin_amdgcn_mfma_f32_16x16x32_bf16(pa, bv, oc[nt], 0, 0, 0);
    }
  }

  float accd[4] = {};
#pragma unroll
  for (int r = 0; r < 4; ++r) {
    const float invr = __shfl(inv, quad * 4 + r);  // 1/sum for output row quad*4+r
#pragma unroll
    for (int nt = 0; nt < 4; ++nt) {
      const float hp = oc[nt][r] * invr;
      accd[nt] += (hp > 0.f) ? hp : (fexp(hp) - 1.0f);
    }
  }
#pragma unroll
  for (int nt = 0; nt < 4; ++nt) {
    accd[nt] += __shfl_xor(accd[nt], 16);
    accd[nt] += __shfl_xor(accd[nt], 32);
  }
  if (quad == 0) {
#pragma unroll
    for (int nt = 0; nt < 4; ++nt) redc[w][nt * 16 + l15] = accd[nt];
  }
  __syncthreads();
  if (w == 0) {
    const float tot = redc[0][lane] + redc[1][lane] + redc[2][lane] + redc[3][lane];
    tgf[b * D + h * 64 + lane] = tot * (1.0f / T);
  }
}

// image GAT (dense, cooperative per-tile — R6 version), one block per (b,h).
// smem: VT[64][232]@0, Ps[16][232]@29696, srcs@37120, dsts@37904,
// asv@38688, adv@38944. (<=49152)
__device__ __forceinline__ void image_gat_body(
    char* smem, int h, int b,
    const unsigned short* __restrict__ Wh, int ldw, const float* __restrict__ ai,
    const int* __restrict__ adj, float* __restrict__ igf) {
  const int tid = threadIdx.x, lane = tid & 63, w = tid >> 6;
  const int quad = lane >> 4, l15 = lane & 15;

  unsigned short (*VT)[232] = (unsigned short(*)[232])smem;
  unsigned short (*Ps)[232] = (unsigned short(*)[232])(smem + 29696);
  float* srcs = (float*)(smem + 37120);
  float* dsts = (float*)(smem + 37904);
  float* asv = (float*)(smem + 38688);
  float* adv = (float*)(smem + 38944);

  if (tid < 64) { asv[tid] = ai[tid]; adv[tid] = ai[64 + tid]; }
  {
    const int f = lane;
    const unsigned short* wbase = Wh + (size_t)(b * P) * ldw + h * 64 + f;
    for (int nb = w; nb < 28; nb += 4) {
      short8 v;
#pragma unroll
      for (int z = 0; z < 8; ++z) {
        const int p = nb * 8 + z;
        v[z] = (p < P) ? (short)wbase[(size_t)p * ldw] : (short)0;
      }
      *(short8*)&VT[f][nb * 8] = v;
    }
  }
  __syncthreads();

  if (tid < P) {
    float s = 0.f, dd = 0.f;
#pragma unroll 8
    for (int f = 0; f < 64; ++f) {
      const float wv = bf2f(VT[f][tid]);
      s += wv * asv[f];
      dd += wv * adv[f];
    }
    srcs[tid] = s;
    dsts[tid] = dd;
  }
  __syncthreads();

  const int rloc = tid >> 4;     // 0..15: local row within tile
  const int cslot = tid & 15;    // 0..15: column slot
  float accw = 0.f;              // running col-sum for col (w*16 + l15)

  for (int tile = 0; tile < 13; ++tile) {
    const int i = tile * 16 + rloc;
    const int ii = (i < P) ? i : (P - 1);
    const float si = srcs[ii];
    const int* ar = adj + ii * P;
    int msk[13];
#pragma unroll
    for (int k = 0; k < 13; ++k) {
      const int jc = k * 16 + cslot;
      msk[k] = (jc < P) ? ar[jc] : 0;
    }
    float pvv[13];
    float sm = 0.f;
#pragma unroll
    for (int k = 0; k < 13; ++k) {
      const int jc = k * 16 + cslot;
      float p = 0.f;
      if (jc < P && msk[k] != 0) {
        float e = si + dsts[jc];
        e = (e >= 0.f) ? e : 0.2f * e;
        p = fexp(e);
      }
      pvv[k] = p;
      sm += p;
    }
    sm += __shfl_xor(sm, 1);
    sm += __shfl_xor(sm, 2);
    sm += __shfl_xor(sm, 4);
    sm += __shfl_xor(sm, 8);
    const float inv = frcp(sm);
#pragma unroll
    for (int k = 0; k < 13; ++k)
      Ps[rloc][k * 16 + cslot] = f2bf(pvv[k] * inv);
    Ps[rloc][208 + cslot] = 0;
    __syncthreads();

    floatx4 oc = {};
#pragma unroll
    for (int ks = 0; ks < 7; ++ks) {
      const short8 pa = *(const short8*)&Ps[l15][ks * 32 + quad * 8];
      const short8 bvv = *(const short8*)&VT[w * 16 + l15][ks * 32 + quad * 8];
      oc = __builtin_amdgcn_mfma_f32_16x16x32_bf16(pa, bvv, oc, 0, 0, 0);
    }
#pragma unroll
    for (int r = 0; r < 4; ++r) {
      const int io = tile * 16 + quad * 4 + r;
      if (io < P) {
        const float hp = oc[r];
        accw += (hp > 0.f) ? hp : (fexp(hp) - 1.0f);
      }
    }
    __syncthreads();   // before next tile's score overwrites Ps
  }

  accw += __shfl_xor(accw, 16);
  accw += __shfl_xor(accw, 32);
  if (quad == 0)
    igf[b * D + h * 64 + w * 16 + l15] = accw * (1.0f / P);
}

// f_global tile: jt in 0..11, b in 0..31. smem: red[4][64]@0.
__device__ __forceinline__ void fglob_body(
    char* smem, int jt, int b,
    const float* __restrict__ clip_t, const float* __restrict__ Wp,
    const float* __restrict__ bp, float* __restrict__ fglob) {
  const int j = threadIdx.x & 63, kc = threadIdx.x >> 6;
  float s = 0.f;
  const float* ct = clip_t + b * 512;
#pragma unroll 4
  for (int k = kc * 128; k < kc * 128 + 128; ++k)
    s += ct[k] * Wp[(size_t)k * D + jt * 64 + j];
  float (*red)[64] = (float(*)[64])smem;
  red[kc][j] = s;
  __syncthreads();
  if (kc == 0)
    fglob[b * D + jt * 64 + j] = red[0][j] + red[1][j] + red[2][j] + red[3][j] + bp[jt * 64 + j];
}

// ---- combo kernel: wo-GEMM (MFMA-bound) + GATs + fglob (latency-bound) in one
// launch -> mutual latency hiding + full machine fill. 1344 blocks:
// [0,192): wo split-K dual f32 (dispatched first: it is on the critical path)
// [192,576): text GAT; [576,960): image GAT; [960,1344): fglob
__global__ __launch_bounds__(256) void combo_kernel(
    GemmJob jwo0, GemmJob jwo1,
    const unsigned short* __restrict__ qa_bf,
    const int* __restrict__ text_adj, const float* __restrict__ at,
    float* __restrict__ tgf,
    const unsigned short* __restrict__ whi, int ldw_i,
    const float* __restrict__ ai, const int* __restrict__ image_adj,
    float* __restrict__ igf,
    const float* __restrict__ clip_t, const float* __restrict__ Wp,
    const float* __restrict__ bp, float* __restrict__ fglob) {
  __shared__ __align__(16) char smem[49152];
  const int bid = blockIdx.x;
  if (bid < 192) {
    const bool first = bid < 96;
    const GemmJob& j = first ? jwo0 : jwo1;
    const int orig = first ? bid : bid - 96;
    const int b2 = xcd_remap(orig, 96);
    gemm_body<false>(j, b2 % j.colTiles, b2 / j.colTiles, threadIdx.x, smem);
  } else if (bid < 576) {
    const int idx = bid - 192;
    text_gat_body(smem, idx % 12, idx / 12, qa_bf + 768, 1536, text_adj, at, tgf);
  } else if (bid < 960) {
    const int idx = bid - 576;
    image_gat_body(smem, idx % 12, idx / 12, whi, ldw_i, ai, image_adj, igf);
  } else {
    const int idx = bid - 960;
    fglob_body(smem, idx % 12, idx / 12, clip_t, Wp, bp, fglob);
  }
}

// ---------------- token: grid (12, B). upd = upd0 + upd1 (split-K partials) ----------------
__global__ __launch_bounds__(256) void token_kernel(
    const float* __restrict__ upd0, const float* __restrict__ upd1,
    const float* __restrict__ img,
    float* __restrict__ f_token, float* __restrict__ s_token) {
  const int jt = blockIdx.x, b = blockIdx.y;
  const int l = threadIdx.x & 63, tg = threadIdx.x >> 6;
  const int d = jt * 64 + l;
  float fs = 0.f, ss = 0.f;
#pragma unroll 4
  for (int tt = 0; tt < 16; ++tt) {
    const int t = tg * 16 + tt;
    const size_t idx = (size_t)(b * T + t) * D + d;
    const float u = upd0[idx] + upd1[idx];
    fs += u;
    ss += u * img[(size_t)(b * P + t) * D + d];
  }
  __shared__ float red[4][64];
  __shared__ float sred[4];
  red[tg][l] = fs;
  const float sw = wave_sum(ss);
  if (l == 0) sred[tg] = sw;
  __syncthreads();
  if (tg == 0) {
    f_token[(size_t)b * D + d] =
        (red[0][l] + red[1][l] + red[2][l] + red[3][l]) * (1.0f / T);
    if (threadIdx.x == 0)
      atomicAdd(&s_token[b], (sred[0] + sred[1] + sred[2] + sred[3]) * (1.0f / T));
  }
}

// ---------------- Xc = [f_token; tgf; fglob] @ c1w : grid (6, 96) ----------------
__global__ __launch_bounds__(256) void xc1_kernel(
    const float* __restrict__ ftok, const float* __restrict__ tgf,
    const float* __restrict__ fglob, const float* __restrict__ c1w,
    float* __restrict__ Xc) {
  const int jt = blockIdx.x;
  const int r = blockIdx.y;
  const int b = r & 31, which = r >> 5;
  const float* src = (which == 0 ? ftok : which == 1 ? tgf : fglob) + (size_t)b * D;
  const int j = threadIdx.x & 63, kc = threadIdx.x >> 6;
  const int col = jt * 64 + j;
  float s = 0.f;
#pragma unroll 4
  for (int k = kc * 192; k < kc * 192 + 192; ++k)
    s += src[k] * c1w[(size_t)k * 384 + col];
  __shared__ float red[4][64];
  red[kc][j] = s;
  __syncthreads();
  if (kc == 0)
    Xc[(size_t)r * 384 + col] = red[0][j] + red[1][j] + red[2][j] + red[3][j];
}

// ---------------- final fusion kernel: one block per b ----------------
__device__ __forceinline__ float block_sum(float v, float* red4) {
  v = wave_sum(v);
  __syncthreads();
  if ((threadIdx.x & 63) == 0) red4[threadIdx.x >> 6] = v;
  __syncthreads();
  return red4[0] + red4[1] + red4[2] + red4[3];
}

__global__ __launch_bounds__(256) void final_kernel(
    const float* __restrict__ tgf, const float* __restrict__ igf,
    const float* __restrict__ clip_t, const float* __restrict__ clip_i,
    const float* __restrict__ logit_scale, const float* __restrict__ s_token,
    const float* __restrict__ Xc,
    const float* __restrict__ f1w, const float* __restrict__ f1b,
    const float* __restrict__ f2w, const float* __restrict__ f2b,
    const float* __restrict__ c1b,
    const float* __restrict__ c2w, const float* __restrict__ c2b,
    float* __restrict__ out) {
  const int b = blockIdx.x, tid = threadIdx.x;
  __shared__ float red[4];
  __shared__ float sres[4];
  __shared__ float hid[384];

  float d0 = 0.f, d1 = 0.f, d2 = 0.f;
  for (int i = tid; i < D; i += 256) {
    float x = tgf[b * D + i], y = igf[b * D + i];
    d0 += x * y; d1 += x * x; d2 += y * y;
  }
  float dot_ti = block_sum(d0, red);
  float n_t = sqrtf(block_sum(d1, red));
  float n_i = sqrtf(block_sum(d2, red));
  float s_phrase = dot_ti / (fmaxf(n_t, 1e-8f) * fmaxf(n_i, 1e-8f));

  float c0 = 0.f, c1 = 0.f, c2 = 0.f;
  for (int i = tid; i < 512; i += 256) {
    float x = clip_t[b * 512 + i], y = clip_i[b * 512 + i];
    c0 += x * y; c1 += x * x; c2 += y * y;
  }
  float dc = block_sum(c0, red);
  float nt2 = sqrtf(block_sum(c1, red));
  float ni2 = sqrtf(block_sum(c2, red));
  float s_global = expf(logit_scale[0]) * dc / (fmaxf(nt2, 1e-8f) * fmaxf(ni2, 1e-8f));

  if (tid == 0) {
    float s3[3] = { s_token[b], s_phrase, s_global };
    float h1[16];
    for (int j = 0; j < 16; ++j) {
      float a = f1b[j];
      for (int i2 = 0; i2 < 3; ++i2) a += s3[i2] * f1w[i2 * 16 + j];
      h1[j] = 0.5f * a * (1.0f + erff(a * 0.70710678118654752f));
    }
    for (int j = 0; j < 3; ++j) {
      float a = f2b[j];
      for (int i2 = 0; i2 < 16; ++i2) a += h1[i2] * f2w[i2 * 3 + j];
      sres[j] = 1.0f / (1.0f + expf(-a));
    }
  }
  __syncthreads();
  const float w0 = sres[0], w1 = sres[1], w2 = sres[2];

  for (int j = tid; j < 384; j += 256) {
    const float a = w0 * Xc[(size_t)b * 384 + j] +
                    w1 * Xc[(size_t)(32 + b) * 384 + j] +
                    w2 * Xc[(size_t)(64 + b) * 384 + j] + c1b[j];
    hid[j] = fmaxf(a, 0.0f);
  }
  __syncthreads();

  float p0 = 0.f, p1 = 0.f;
  for (int k2 = tid; k2 < 384; k2 += 256) {
    p0 += hid[k2] * c2w[k2 * 2 + 0];
    p1 += hid[k2] * c2w[k2 * 2 + 1];
  }
  p0 = block_sum(p0, red);
  p1 = block_sum(p1, red);
  if (tid == 0) {
    out[b * 2 + 0] = p0 + c2b[0];
    out[b * 2 + 1] = p1 + c2b[1];
  }
}

// ---------------- launch ----------------
extern "C" void kernel_launch(void* const* d_in, const int* in_sizes, int n_in,
                              void* d_out, int out_size, void* d_ws, size_t ws_size,
                              hipStream_t stream) {
  const float* text   = (const float*)d_in[0];
  const float* img    = (const float*)d_in[1];
  const float* clip_t = (const float*)d_in[2];
  const float* clip_i = (const float*)d_in[3];
  const float* lscale = (const float*)d_in[4];
  const float* wq = (const float*)d_in[5];
  const float* bq = (const float*)d_in[6];
  const float* wk = (const float*)d_in[7];
  const float* bk = (const float*)d_in[8];
  const float* wv = (const float*)d_in[9];
  const float* bv = (const float*)d_in[10];
  const float* wo = (const float*)d_in[11];
  const float* bo = (const float*)d_in[12];
  const float* Wt = (const float*)d_in[13];
  const float* at = (const float*)d_in[14];
  const float* Wi = (const float*)d_in[15];
  const float* ai = (const float*)d_in[16];
  const float* Wp = (const float*)d_in[17];
  const float* bp = (const float*)d_in[18];
  const float* f1w = (const float*)d_in[19];
  const float* f1b = (const float*)d_in[20];
  const float* f2w = (const float*)d_in[21];
  const float* f2b = (const float*)d_in[22];
  const float* c1w = (const float*)d_in[23];
  const float* c1b = (const float*)d_in[24];
  const float* c2w = (const float*)d_in[25];
  const float* c2b = (const float*)d_in[26];
  const int* text_adj  = (const int*)d_in[27];
  const int* image_adj = (const int*)d_in[28];
  float* out = (float*)d_out;

  const size_t nTD = (size_t)B * T * D;   // 1,572,864
  const size_t nPD = (size_t)B * P * D;   // 4,816,896
  const size_t nWW = (size_t)D * D;       // 589,824

  // ---- workspace layout (no aliasing) ----
  float* fbuf = (float*)d_ws;
  size_t o = 0;
  float* upd0    = fbuf + o; o += nTD;     // wo GEMM split-K partial 0 (with bias)
  float* upd1    = fbuf + o; o += nTD;     // partial 1
  float* ftok    = fbuf + o; o += (size_t)B * D;
  float* stok    = fbuf + o; o += 32;
  float* tgf     = fbuf + o; o += (size_t)B * D;
  float* igf     = fbuf + o; o += (size_t)B * D;
  float* fglob   = fbuf + o; o += (size_t)B * D;
  float* bcat_t  = fbuf + o; o += 1536;
  float* bcat_i3 = fbuf + o; o += 2304;
  float* Xc      = fbuf + o; o += (size_t)96 * 384;
  unsigned short* sbuf = (unsigned short*)(fbuf + o);
  size_t so = 0;
  unsigned short* kvw_bf    = sbuf + so; so += 3 * nPD;  // [B*P][2304] bf16: k|v|Wh_i
  unsigned short* qa_bf     = sbuf + so; so += 2 * nTD;  // [B*T][1536] bf16: q|Wh_t
  unsigned short* text_bf   = sbuf + so; so += nTD;
  unsigned short* img_bf    = sbuf + so; so += nPD;
  unsigned short* att_bf    = sbuf + so; so += nTD;
  unsigned short* wcat_txt  = sbuf + so; so += 2 * nWW;  // wq^T | Wt^T
  unsigned short* wcat_img3 = sbuf + so; so += 3 * nWW;  // wk^T | wv^T | Wi^T
  unsigned short* wo_t      = sbuf + so; so += nWW;

  // ---- fused prep: weight cast-transposes + biases + activation casts ----
  WPack wp;
  wp.src[0] = wq; wp.dst[0] = wcat_txt;
  wp.src[1] = Wt; wp.dst[1] = wcat_txt + nWW;
  wp.src[2] = wk; wp.dst[2] = wcat_img3;
  wp.src[3] = wv; wp.dst[3] = wcat_img3 + nWW;
  wp.src[4] = Wi; wp.dst[4] = wcat_img3 + 2 * nWW;
  wp.src[5] = wo; wp.dst[5] = wo_t;
  {
    const int n40 = (int)(nTD / 4), n41 = (int)(nPD / 4);
    prep_kernel<<<9708, 256, 0, stream>>>(wp, text, text_bf, n40, img, img_bf, n41,
                                          bq, bk, bv, bcat_t, bcat_i3, stok);
  }

  const int MT = B * T;   // 2048
  const int MP = B * P;   // 6272

  // ---- fused projections (bf16 C output): one dual launch ----
  GemmJob jimg;  // kvw_bf = img @ [wk|wv|Wi] + [bk,bv,0]
  jimg.A = img_bf; jimg.Bt = wcat_img3; jimg.bias = bcat_i3; jimg.C = kvw_bf;
  jimg.N = 2304; jimg.K = D; jimg.lda = D; jimg.ldb = D; jimg.colTiles = 2304 / 128;
  GemmJob jtxt;  // qa_bf = text @ [wq|Wt] + [bq,0]
  jtxt.A = text_bf; jtxt.Bt = wcat_txt; jtxt.bias = bcat_t; jtxt.C = qa_bf;
  jtxt.N = 1536; jtxt.K = D; jtxt.lda = D; jtxt.ldb = D; jtxt.colTiles = 1536 / 128;
  const int splitBlocks = (2304 / 128) * (MP / 128);                // 882
  const int totalBlocks = splitBlocks + (1536 / 128) * (MT / 128);  // 882 + 192
  gemm_mfma_dual_bf16<<<totalBlocks, 256, 0, stream>>>(jimg, jtxt, splitBlocks, totalBlocks);

  // ---- attention (feeds the wo GEMM in combo) ----
  attn_kernel<<<dim3(H, B), 256, 0, stream>>>(qa_bf, kvw_bf, att_bf);

  // ---- combo: wo-GEMM split-K x2 + text GAT + image GAT + fglob ----
  GemmJob jwo0;  // upd0 = att[:, :384] @ wo_t[:, :384]^T + bo
  jwo0.A = att_bf; jwo0.Bt = wo_t; jwo0.bias = bo; jwo0.C = upd0;
  jwo0.N = D; jwo0.K = 384; jwo0.lda = D; jwo0.ldb = D; jwo0.colTiles = D / 128;
  GemmJob jwo1;  // upd1 = att[:, 384:] @ wo_t[:, 384:]^T
  jwo1.A = att_bf + 384; jwo1.Bt = wo_t + 384; jwo1.bias = nullptr; jwo1.C = upd1;
  jwo1.N = D; jwo1.K = 384; jwo1.lda = D; jwo1.ldb = D; jwo1.colTiles = D / 128;
  const unsigned short* whi_bf = kvw_bf + 1536;
  combo_kernel<<<1344, 256, 0, stream>>>(
      jwo0, jwo1,
      qa_bf, text_adj, at, tgf,
      whi_bf, 2304, ai, image_adj, igf,
      clip_t, Wp, bp, fglob);

  token_kernel<<<dim3(12, B), 256, 0, stream>>>(upd0, upd1, img, ftok, stok);
  xc1_kernel<<<dim3(6, 96), 256, 0, stream>>>(ftok, tgf, fglob, c1w, Xc);
  final_kernel<<<B, 256, 0, stream>>>(tgf, igf, clip_t, clip_i, lscale, stok, Xc,
                                      f1w, f1b, f2w, f2b, c1b, c2w, c2b, out);
}

// Round 10
// 249.615 us; speedup vs baseline: 1.1369x; 1.0536x over previous
//
#include <hip/hip_runtime.h>
#include <hip/hip_bf16.h>
#include <math.h>

// Problem constants
#define B 32
#define T 64
#define P 196
#define D 768
#define H 12

typedef __attribute__((ext_vector_type(8))) short short8;
typedef __attribute__((ext_vector_type(4))) float floatx4;

// ---------------- helpers ----------------
__device__ __forceinline__ float wave_sum(float v) {
#pragma unroll
  for (int o = 32; o > 0; o >>= 1) v += __shfl_xor(v, o);
  return v;
}
__device__ __forceinline__ unsigned short f2bf(float x) {
  unsigned u = __float_as_uint(x);
  u += 0x7FFFu + ((u >> 16) & 1u);   // round-to-nearest-even
  return (unsigned short)(u >> 16);
}
__device__ __forceinline__ float bf2f(unsigned short x) {
  return __uint_as_float((unsigned)x << 16);
}
// fast exp: native v_exp_f32 — ~2 VALU instrs vs ~25 for libm expf
__device__ __forceinline__ float fexp(float x) { return __expf(x); }
__device__ __forceinline__ float frcp(float x) { return __builtin_amdgcn_rcpf(x); }
// async global->LDS, 16B per lane; LDS dest = wave-uniform base + lane*16
__device__ __forceinline__ void async_cp16(const unsigned short* g, unsigned short* l) {
  __builtin_amdgcn_global_load_lds(
      (const __attribute__((address_space(1))) unsigned int*)g,
      (__attribute__((address_space(3))) unsigned int*)l, 16, 0, 0);
}
// bijective XCD-chunked remap (m204): each XCD gets one contiguous chunk of tiles
__device__ __forceinline__ int xcd_remap(int orig, int nwg) {
  const int q = nwg >> 3, r = nwg & 7;
  const int x = orig & 7, o = orig >> 3;
  return (x < r ? x * (q + 1) : r * (q + 1) + (x - r) * q) + o;
}

// ---------------- fused prep: 6x weight cast-transpose + activation casts + biases ----
struct WPack {
  const float* src[6];
  unsigned short* dst[6];
};
// blocks [0,3456): transpose6 (z = bid/576, 24x24 tiles of 32x32)
// blocks [3456,9696): cast_rows2
// blocks [9696,9792): biases + zero stok + zero ftok (ftok = 24576 floats)
__global__ __launch_bounds__(256) void prep_kernel(
    WPack p,
    const float* __restrict__ text, unsigned short* __restrict__ text_bf, int n40,
    const float* __restrict__ img, unsigned short* __restrict__ img_bf, int n41,
    const float* __restrict__ bq, const float* __restrict__ bk,
    const float* __restrict__ bv,
    float* __restrict__ bt, float* __restrict__ bi, float* __restrict__ stok,
    float* __restrict__ ftok) {
  const int bid = blockIdx.x;
  if (bid < 3456) {
    __shared__ float tile[32][33];
    const int z = bid / 576, rem = bid % 576;
    const int bx = rem % 24, by = rem / 24;
    const float* W = p.src[z];
    unsigned short* Wt = p.dst[z];
    const int tx = threadIdx.x & 31, ty = threadIdx.x >> 5;  // ty 0..7
    const int n0 = bx * 32, k0 = by * 32;
#pragma unroll
    for (int r = 0; r < 4; ++r)
      tile[ty + 8 * r][tx] = W[(size_t)(k0 + ty + 8 * r) * D + n0 + tx];
    __syncthreads();
#pragma unroll
    for (int r = 0; r < 4; ++r)
      Wt[(size_t)(n0 + ty + 8 * r) * D + k0 + tx] = f2bf(tile[tx][ty + 8 * r]);
  } else if (bid < 9696) {
    int i = (bid - 3456) * 256 + threadIdx.x;
    const float* X;
    unsigned short* Y;
    int idx;
    if (i < n40) { X = text; Y = text_bf; idx = i; }
    else if (i < n40 + n41) { X = img; Y = img_bf; idx = i - n40; }
    else return;
    float4 vv = ((const float4*)X)[idx];
    ushort4 o;
    o.x = f2bf(vv.x); o.y = f2bf(vv.y); o.z = f2bf(vv.z); o.w = f2bf(vv.w);
    ((ushort4*)Y)[idx] = o;
  } else {
    int i = (bid - 9696) * 256 + threadIdx.x;   // 0..24575 == B*D
    ftok[i] = 0.f;
    if (i < 32) stok[i] = 0.f;
    if (i < 768) { bt[i] = bq[i]; bi[i] = bk[i]; }
    else if (i < 1536) { bt[i] = 0.f; bi[i] = bv[i - 768]; }
    else if (i < 2304) { bi[i] = 0.f; }
  }
}

// ---------------- bf16 MFMA GEMM body (LDS arena passed in) ----------------
// Phase-pipelined: phase s: STAGE buf[(s+2)%3] -> vmcnt(4)+lgkmcnt(0) -> ONE
// barrier -> issue ds_reads for frag(s+1) -> 16 register-only MFMAs on frag(s).
// Fragment regs double-buffer; LDS buffers cycle %3; period-6 unroll (rule #20).
// Requires K % 192 == 0 (here K in {384, 768}). Needs 49152B of LDS arena.
// Swizzle (T2, rule #21): linear LDS dest + inverse-swizzled global source col
// + swizzled read col -> 0 bank conflicts (verified R4).
// TOKEN epilogue (wo GEMM): upd is consumed ONLY by f_token/s_token, both
// linear in the split-K partials -> compute them here via atomics and skip the
// C write entirely (removes the 38MB upd round-trip + the token kernel).
// Wave rows lie in ONE b (m_off in {0,64}, row0%128==0); t = 16i+quad*4+r.
struct GemmJob {
  const unsigned short* A;   // [M][*] bf16, row stride lda
  const unsigned short* Bt;  // [N][*] bf16, row stride ldb
  const float* bias;
  void* C;                   // fp32 or bf16 per template (unused if TOKEN)
  int N, K, lda, ldb, colTiles;
};

template <bool BF16OUT, bool TOKEN>
__device__ __forceinline__ void gemm_body(const GemmJob& j, int bx, int by, int tid,
                                          char* smem,
                                          const float* timg, float* ftok,
                                          float* stok) {
  unsigned short (*As)[128][32] = (unsigned short(*)[128][32])smem;
  unsigned short (*Bs)[128][32] = (unsigned short(*)[128][32])(smem + 24576);
  const int lane = tid & 63;
  const int w = tid >> 6;
  const int quad = lane >> 4;
  const int l15 = lane & 15;
  const int row0 = by * 128;
  const int col0 = bx * 128;
  const int m_off = (w & 1) * 64;
  const int n_off = (w >> 1) * 64;
  const int N = j.N, K = j.K;

  const int srow = 16 * w + (lane >> 2);
  const int scol = (((lane & 3) ^ ((lane >> 3) & 3))) * 8;
  const unsigned short* gA0 = j.A + (size_t)(row0 + srow) * j.lda + scol;
  const unsigned short* gA1 = j.A + (size_t)(row0 + srow + 64) * j.lda + scol;
  const unsigned short* gB0 = j.Bt + (size_t)(col0 + srow) * j.ldb + scol;
  const unsigned short* gB1 = j.Bt + (size_t)(col0 + srow + 64) * j.ldb + scol;

  const int rdc = (quad ^ ((l15 >> 1) & 3)) * 8;

  floatx4 acc[4][4] = {};
  short8 fA[4], fB_[4];   // even-phase fragments
  short8 gA_[4], gB_[4];  // odd-phase fragments

#define STAGE(buf, kk)                                   \
  do {                                                   \
    async_cp16(gA0 + (kk), &As[buf][16 * w][0]);         \
    async_cp16(gA1 + (kk), &As[buf][64 + 16 * w][0]);    \
    async_cp16(gB0 + (kk), &Bs[buf][16 * w][0]);         \
    async_cp16(gB1 + (kk), &Bs[buf][64 + 16 * w][0]);    \
  } while (0)

  auto RD = [&](short8 (&AF)[4], short8 (&BF)[4], int buf) {
#pragma unroll
    for (int i = 0; i < 4; ++i)
      AF[i] = *(const short8*)&As[buf][m_off + 16 * i + l15][rdc];
#pragma unroll
    for (int j2 = 0; j2 < 4; ++j2)
      BF[j2] = *(const short8*)&Bs[buf][n_off + 16 * j2 + l15][rdc];
  };
  auto MM = [&](short8 (&AF)[4], short8 (&BF)[4]) {
#pragma unroll
    for (int i = 0; i < 4; ++i)
#pragma unroll
      for (int j2 = 0; j2 < 4; ++j2)
        acc[i][j2] = __builtin_amdgcn_mfma_f32_16x16x32_bf16(AF[i], BF[j2], acc[i][j2], 0, 0, 0);
  };
  auto PHASE = [&](short8 (&curA)[4], short8 (&curB)[4],
                   short8 (&nxtA)[4], short8 (&nxtB)[4],
                   int stageBuf, int readBuf, int kk) {
    if (kk + 64 < K) {
      STAGE(stageBuf, kk + 64);
      asm volatile("s_waitcnt vmcnt(4) lgkmcnt(0)" ::: "memory");
      __builtin_amdgcn_s_barrier();
      __builtin_amdgcn_sched_barrier(0);
      RD(nxtA, nxtB, readBuf);
    } else if (kk + 32 < K) {
      asm volatile("s_waitcnt vmcnt(0) lgkmcnt(0)" ::: "memory");
      __builtin_amdgcn_s_barrier();
      __builtin_amdgcn_sched_barrier(0);
      RD(nxtA, nxtB, readBuf);
    }
    MM(curA, curB);
  };

  // prologue: stage steps 0,1; wait buf0; read frag(0) into set F
  STAGE(0, 0);
  STAGE(1, 32);
  asm volatile("s_waitcnt vmcnt(4)" ::: "memory");
  __builtin_amdgcn_s_barrier();
  __builtin_amdgcn_sched_barrier(0);
  RD(fA, fB_, 0);

  for (int k0 = 0; k0 < K; k0 += 192) {
    PHASE(fA, fB_, gA_, gB_, 2, 1, k0);        // s%6==0
    PHASE(gA_, gB_, fA, fB_, 0, 2, k0 + 32);   // s%6==1
    PHASE(fA, fB_, gA_, gB_, 1, 0, k0 + 64);   // s%6==2
    PHASE(gA_, gB_, fA, fB_, 2, 1, k0 + 96);   // s%6==3
    PHASE(fA, fB_, gA_, gB_, 0, 2, k0 + 128);  // s%6==4
    PHASE(gA_, gB_, fA, fB_, 1, 0, k0 + 160);  // s%6==5
  }
#undef STAGE

  if constexpr (TOKEN) {
    // fused token epilogue: ftok[b][cg] += (1/T) * col-partials;
    // stok[b] += (1/T) * sum(val * img[b,t,cg]).  b is wave-uniform.
    const int bb = (row0 + m_off) >> 6;
    float sval = 0.f;
#pragma unroll
    for (int jj = 0; jj < 4; ++jj) {
      const int cg = col0 + n_off + 16 * jj + l15;
      const float bv = j.bias ? j.bias[cg] : 0.0f;
      float fsum = 0.f;
#pragma unroll
      for (int i = 0; i < 4; ++i) {
#pragma unroll
        for (int r = 0; r < 4; ++r) {
          const float val = acc[i][jj][r] + bv;
          const int t = 16 * i + quad * 4 + r;
          fsum += val;
          sval += val * timg[(size_t)(bb * P + t) * D + cg];
        }
      }
      atomicAdd(&ftok[(size_t)bb * D + cg], fsum * (1.0f / T));
    }
    const float sv = wave_sum(sval);
    if (lane == 0) atomicAdd(&stok[bb], sv * (1.0f / T));
  } else {
#pragma unroll
    for (int jj = 0; jj < 4; ++jj) {
      const int cg = col0 + n_off + 16 * jj + l15;
      const float bv = j.bias ? j.bias[cg] : 0.0f;
#pragma unroll
      for (int i = 0; i < 4; ++i) {
        const int rbase = row0 + m_off + 16 * i + quad * 4;
#pragma unroll
        for (int r = 0; r < 4; ++r) {
          const float val = acc[i][jj][r] + bv;
          const size_t idx = (size_t)(rbase + r) * N + cg;
          if (BF16OUT) ((unsigned short*)j.C)[idx] = f2bf(val);
          else ((float*)j.C)[idx] = val;
        }
      }
    }
  }
}

// two independent GEMMs in one launch; blockIdx.x < split -> job0 else job1
__global__ __launch_bounds__(256) void gemm_mfma_dual_bf16(GemmJob j0, GemmJob j1,
                                                           int split, int total) {
  __shared__ __align__(16) char gsmem[49152];
  const bool first = ((int)blockIdx.x < split);
  const GemmJob& j = first ? j0 : j1;
  const int orig = first ? blockIdx.x : (blockIdx.x - split);
  const int bid = xcd_remap(orig, first ? split : total - split);
  const int bx = bid % j.colTiles;
  const int by = bid / j.colTiles;
  gemm_body<true, false>(j, bx, by, threadIdx.x, gsmem, nullptr, nullptr, nullptr);
}

// ---------------- device bodies (share LDS arenas) --------

// MFMA cross attention, one block per (b,h), 4 waves.
// smem layout: Ks[196][72] (union Ps[4][16][232]) @0 (29952B); VT[64][232] @29952.
__device__ __forceinline__ void attn_body(
    char* smem, int h, int b,
    const unsigned short* __restrict__ qa, const unsigned short* __restrict__ kvw,
    unsigned short* __restrict__ attout) {
  const int tid = threadIdx.x, lane = tid & 63, w = tid >> 6;
  const int quad = lane >> 4, l15 = lane & 15;

  unsigned short (*Ks)[72] = (unsigned short(*)[72])smem;
  unsigned short (*Ps)[16][232] = (unsigned short(*)[16][232])smem;
  unsigned short (*VT)[232] = (unsigned short(*)[232])(smem + 29952);

  // Q fragments first: independent global loads overlap the staging below
  short8 aq[2];
#pragma unroll
  for (int ks = 0; ks < 2; ++ks)
    aq[ks] = *(const short8*)(qa + (size_t)(b * T + 16 * w + l15) * 1536 + h * 64 +
                              32 * ks + quad * 8);

  // K rows: one short8 global load -> one b128 LDS write
  for (int i = tid; i < P * 8; i += 256) {
    const int p = i >> 3, dg = i & 7;
    const short8 k8 =
        *(const short8*)(kvw + (size_t)(b * P + p) * 2304 + h * 64 + dg * 8);
    *(short8*)&Ks[p][dg * 8] = k8;
  }
  // V^T: lane owns column d; coalesced-across-lanes b16 loads -> b128 LDS write.
  {
    const int d = lane;
    const unsigned short* vbase = kvw + (size_t)b * P * 2304 + 768 + h * 64 + d;
    for (int pb = w; pb < 28; pb += 4) {
      short8 v;
#pragma unroll
      for (int z = 0; z < 8; ++z) {
        const int p = pb * 8 + z;
        v[z] = (p < P) ? (short)vbase[(size_t)p * 2304] : (short)0;
      }
      *(short8*)&VT[d][pb * 8] = v;
    }
  }
  __syncthreads();

  floatx4 sc[13];
#pragma unroll
  for (int tile = 0; tile < 13; ++tile) {
    int p = tile * 16 + l15;
    if (p > 195) p = 195;
    short8 bk0 = *(const short8*)&Ks[p][quad * 8];
    short8 bk1 = *(const short8*)&Ks[p][32 + quad * 8];
    floatx4 c = {};
    c = __builtin_amdgcn_mfma_f32_16x16x32_bf16(aq[0], bk0, c, 0, 0, 0);
    c = __builtin_amdgcn_mfma_f32_16x16x32_bf16(aq[1], bk1, c, 0, 0, 0);
    sc[tile] = c;
  }

  float mx[4] = {-3.4e38f, -3.4e38f, -3.4e38f, -3.4e38f};
#pragma unroll
  for (int tile = 0; tile < 13; ++tile)
#pragma unroll
    for (int r = 0; r < 4; ++r) {
      float s = sc[tile][r] * 0.125f;
      if (tile == 12 && l15 >= 4) s = -3.0e38f;
      sc[tile][r] = s;
      mx[r] = fmaxf(mx[r], s);
    }
#pragma unroll
  for (int off = 1; off < 16; off <<= 1)
#pragma unroll
    for (int r = 0; r < 4; ++r) mx[r] = fmaxf(mx[r], __shfl_xor(mx[r], off));

  float sm[4] = {};
#pragma unroll
  for (int tile = 0; tile < 13; ++tile)
#pragma unroll
    for (int r = 0; r < 4; ++r) {
      float e = fexp(sc[tile][r] - mx[r]);   // native v_exp (masked lanes -> 0)
      sc[tile][r] = e;
      sm[r] += e;
    }
#pragma unroll
  for (int off = 1; off < 16; off <<= 1)
#pragma unroll
    for (int r = 0; r < 4; ++r) sm[r] += __shfl_xor(sm[r], off);
  float inv[4];
#pragma unroll
  for (int r = 0; r < 4; ++r) inv[r] = frcp(sm[r]);

  __syncthreads();  // all waves done reading Ks before Ps (same LDS) is written

  // store RAW exp (1/sum deferred to epilogue — it is per-(quad,r) lane-local)
#pragma unroll
  for (int tile = 0; tile < 13; ++tile)
#pragma unroll
    for (int r = 0; r < 4; ++r)
      Ps[w][quad * 4 + r][tile * 16 + l15] = f2bf(sc[tile][r]);
#pragma unroll
  for (int r = 0; r < 4; ++r)
    Ps[w][quad * 4 + r][208 + l15] = 0;

  floatx4 oc[4] = {};
#pragma unroll
  for (int ks = 0; ks < 7; ++ks) {
    short8 pa = *(const short8*)&Ps[w][l15][ks * 32 + quad * 8];
#pragma unroll
    for (int nt = 0; nt < 4; ++nt) {
      short8 bv = *(const short8*)&VT[nt * 16 + l15][ks * 32 + quad * 8];
      oc[nt] = __builtin_amdgcn_mfma_f32_16x16x32_bf16(pa, bv, oc[nt], 0, 0, 0);
    }
  }

#pragma unroll
  for (int nt = 0; nt < 4; ++nt)
#pragma unroll
    for (int r = 0; r < 4; ++r)
      attout[(size_t)(b * T + 16 * w + quad * 4 + r) * 768 + h * 64 + nt * 16 + l15] =
          f2bf(oc[nt][r] * inv[r]);
}

// standalone attn kernel: grid (12, 32)
__global__ __launch_bounds__(256) void attn_kernel(
    const unsigned short* __restrict__ qa_bf, const unsigned short* __restrict__ kvw_bf,
    unsigned short* __restrict__ att_bf) {
  __shared__ __align__(16) char smem[59648];
  attn_body(smem, blockIdx.x, blockIdx.y, qa_bf, kvw_bf, att_bf);
}

// text GAT, one block per (b,h). smem: VT[64][72]@0, Ps[4][16][72]@9216,
// srcs@18432, dsts@18688, redc[4][64]@18944, asv@19968, adv@20224. (<=49152)
__device__ __forceinline__ void text_gat_body(
    char* smem, int h, int b,
    const unsigned short* __restrict__ Wh, int ldw, const int* __restrict__ adj,
    const float* __restrict__ at, float* __restrict__ tgf) {
  const int tid = threadIdx.x, lane = tid & 63, w = tid >> 6;
  const int quad = lane >> 4, l15 = lane & 15;

  unsigned short (*VT)[72] = (unsigned short(*)[72])smem;
  unsigned short (*Ps)[16][72] = (unsigned short(*)[16][72])(smem + 9216);
  float* srcs = (float*)(smem + 18432);
  float* dsts = (float*)(smem + 18688);
  float (*redc)[64] = (float(*)[64])(smem + 18944);
  float* asv = (float*)(smem + 19968);
  float* adv = (float*)(smem + 20224);

  if (tid < 64) { asv[tid] = at[tid]; adv[tid] = at[64 + tid]; }
  {
    const int f = lane;
    const unsigned short* wbase = Wh + (size_t)(b * T) * ldw + h * 64 + f;
    for (int nb = w; nb < 8; nb += 4) {
      short8 v;
#pragma unroll
      for (int z = 0; z < 8; ++z)
        v[z] = (short)wbase[(size_t)(nb * 8 + z) * ldw];
      *(short8*)&VT[f][nb * 8] = v;
    }
  }
  __syncthreads();

  if (tid < 64) {
    float s = 0.f, dd = 0.f;
#pragma unroll 8
    for (int f = 0; f < 64; ++f) {
      const float wv = bf2f(VT[f][tid]);
      s += wv * asv[f];
      dd += wv * adv[f];
    }
    srcs[tid] = s;
    dsts[tid] = dd;
  }
  __syncthreads();

  const int i = 16 * w + l15;
  const float si = srcs[i];
  const int* ar = adj + (size_t)b * T * T + i * 64;
  float sm = 0.f;
#pragma unroll 8
  for (int jj = 0; jj < 16; ++jj) {
    const int j = 4 * jj + quad;
    float e = si + dsts[j];
    e = (e >= 0.f) ? e : 0.2f * e;
    const float p = (ar[j] != 0) ? fexp(e) : 0.f;
    sm += p;
    Ps[w][l15][j] = f2bf(p);
  }
  sm += __shfl_xor(sm, 16);
  sm += __shfl_xor(sm, 32);
  const float inv = frcp(sm);

  floatx4 oc[4] = {};
#pragma unroll
  for (int ks = 0; ks < 2; ++ks) {
    const short8 pa = *(const short8*)&Ps[w][l15][ks * 32 + quad * 8];
#pragma unroll
    for (int nt = 0; nt < 4; ++nt) {
      const short8 bv = *(const short8*)&VT[nt * 16 + l15][ks * 32 + quad * 8];
      oc[nt] = __builtin_amdgcn_mfma_f32_16x16x32_bf16(pa, bv, oc[nt], 0, 0, 0);
    }
  }

  float accd[4] = {};
#pragma unroll
  for (int r = 0; r < 4; ++r) {
    const float invr = __shfl(inv, quad * 4 + r);  // 1/sum for output row quad*4+r
#pragma unroll
    for (int nt = 0; nt < 4; ++nt) {
      const float hp = oc[nt][r] * invr;
      accd[nt] += (hp > 0.f) ? hp : (fexp(hp) - 1.0f);
    }
  }
#pragma unroll
  for (int nt = 0; nt < 4; ++nt) {
    accd[nt] += __shfl_xor(accd[nt], 16);
    accd[nt] += __shfl_xor(accd[nt], 32);
  }
  if (quad == 0) {
#pragma unroll
    for (int nt = 0; nt < 4; ++nt) redc[w][nt * 16 + l15] = accd[nt];
  }
  __syncthreads();
  if (w == 0) {
    const float tot = redc[0][lane] + redc[1][lane] + redc[2][lane] + redc[3][lane];
    tgf[b * D + h * 64 + lane] = tot * (1.0f / T);
  }
}

// image GAT (dense, cooperative per-tile), one block per (b,h).
// smem: VT[64][232]@0, Ps[16][232]@29696, srcs@37120, dsts@37904,
// asv@38688, adv@38944. (<=49152)
__device__ __forceinline__ void image_gat_body(
    char* smem, int h, int b,
    const unsigned short* __restrict__ Wh, int ldw, const float* __restrict__ ai,
    const int* __restrict__ adj, float* __restrict__ igf) {
  const int tid = threadIdx.x, lane = tid & 63, w = tid >> 6;
  const int quad = lane >> 4, l15 = lane & 15;

  unsigned short (*VT)[232] = (unsigned short(*)[232])smem;
  unsigned short (*Ps)[232] = (unsigned short(*)[232])(smem + 29696);
  float* srcs = (float*)(smem + 37120);
  float* dsts = (float*)(smem + 37904);
  float* asv = (float*)(smem + 38688);
  float* adv = (float*)(smem + 38944);

  if (tid < 64) { asv[tid] = ai[tid]; adv[tid] = ai[64 + tid]; }
  {
    const int f = lane;
    const unsigned short* wbase = Wh + (size_t)(b * P) * ldw + h * 64 + f;
    for (int nb = w; nb < 28; nb += 4) {
      short8 v;
#pragma unroll
      for (int z = 0; z < 8; ++z) {
        const int p = nb * 8 + z;
        v[z] = (p < P) ? (short)wbase[(size_t)p * ldw] : (short)0;
      }
      *(short8*)&VT[f][nb * 8] = v;
    }
  }
  __syncthreads();

  if (tid < P) {
    float s = 0.f, dd = 0.f;
#pragma unroll 8
    for (int f = 0; f < 64; ++f) {
      const float wv = bf2f(VT[f][tid]);
      s += wv * asv[f];
      dd += wv * adv[f];
    }
    srcs[tid] = s;
    dsts[tid] = dd;
  }
  __syncthreads();

  const int rloc = tid >> 4;     // 0..15: local row within tile
  const int cslot = tid & 15;    // 0..15: column slot
  float accw = 0.f;              // running col-sum for col (w*16 + l15)

  for (int tile = 0; tile < 13; ++tile) {
    const int i = tile * 16 + rloc;
    const int ii = (i < P) ? i : (P - 1);
    const float si = srcs[ii];
    const int* ar = adj + ii * P;
    int msk[13];
#pragma unroll
    for (int k = 0; k < 13; ++k) {
      const int jc = k * 16 + cslot;
      msk[k] = (jc < P) ? ar[jc] : 0;
    }
    float pvv[13];
    float sm = 0.f;
#pragma unroll
    for (int k = 0; k < 13; ++k) {
      const int jc = k * 16 + cslot;
      float p = 0.f;
      if (jc < P && msk[k] != 0) {
        float e = si + dsts[jc];
        e = (e >= 0.f) ? e : 0.2f * e;
        p = fexp(e);
      }
      pvv[k] = p;
      sm += p;
    }
    sm += __shfl_xor(sm, 1);
    sm += __shfl_xor(sm, 2);
    sm += __shfl_xor(sm, 4);
    sm += __shfl_xor(sm, 8);
    const float inv = frcp(sm);
#pragma unroll
    for (int k = 0; k < 13; ++k)
      Ps[rloc][k * 16 + cslot] = f2bf(pvv[k] * inv);
    Ps[rloc][208 + cslot] = 0;
    __syncthreads();

    floatx4 oc = {};
#pragma unroll
    for (int ks = 0; ks < 7; ++ks) {
      const short8 pa = *(const short8*)&Ps[l15][ks * 32 + quad * 8];
      const short8 bvv = *(const short8*)&VT[w * 16 + l15][ks * 32 + quad * 8];
      oc = __builtin_amdgcn_mfma_f32_16x16x32_bf16(pa, bvv, oc, 0, 0, 0);
    }
#pragma unroll
    for (int r = 0; r < 4; ++r) {
      const int io = tile * 16 + quad * 4 + r;
      if (io < P) {
        const float hp = oc[r];
        accw += (hp > 0.f) ? hp : (fexp(hp) - 1.0f);
      }
    }
    __syncthreads();   // before next tile's score overwrites Ps
  }

  accw += __shfl_xor(accw, 16);
  accw += __shfl_xor(accw, 32);
  if (quad == 0)
    igf[b * D + h * 64 + w * 16 + l15] = accw * (1.0f / P);
}

// f_global tile: jt in 0..11, b in 0..31. smem: red[4][64]@0.
__device__ __forceinline__ void fglob_body(
    char* smem, int jt, int b,
    const float* __restrict__ clip_t, const float* __restrict__ Wp,
    const float* __restrict__ bp, float* __restrict__ fglob) {
  const int j = threadIdx.x & 63, kc = threadIdx.x >> 6;
  const float* ct = clip_t + b * 512 + kc * 128;
  const float* wp = Wp + (size_t)(kc * 128) * D + jt * 64 + j;
  float s0 = 0.f, s1 = 0.f, s2 = 0.f, s3 = 0.f;
#pragma unroll
  for (int k = 0; k < 128; k += 4) {
    s0 += ct[k]     * wp[(size_t)k * D];
    s1 += ct[k + 1] * wp[(size_t)(k + 1) * D];
    s2 += ct[k + 2] * wp[(size_t)(k + 2) * D];
    s3 += ct[k + 3] * wp[(size_t)(k + 3) * D];
  }
  float (*red)[64] = (float(*)[64])smem;
  red[kc][j] = (s0 + s1) + (s2 + s3);
  __syncthreads();
  if (kc == 0)
    fglob[b * D + jt * 64 + j] = red[0][j] + red[1][j] + red[2][j] + red[3][j] + bp[jt * 64 + j];
}

// ---- combo kernel: wo-GEMM (MFMA-bound, token-fused epilogue) + GATs + fglob
// (latency-bound) in one launch. 1344 blocks:
// [0,192): wo split-K dual f32+token (first: it is on the critical path)
// [192,576): text GAT; [576,960): image GAT; [960,1344): fglob
__global__ __launch_bounds__(256) void combo_kernel(
    GemmJob jwo0, GemmJob jwo1,
    const float* __restrict__ timg, float* __restrict__ ftok, float* __restrict__ stok,
    const unsigned short* __restrict__ qa_bf,
    const int* __restrict__ text_adj, const float* __restrict__ at,
    float* __restrict__ tgf,
    const unsigned short* __restrict__ whi, int ldw_i,
    const float* __restrict__ ai, const int* __restrict__ image_adj,
    float* __restrict__ igf,
    const float* __restrict__ clip_t, const float* __restrict__ Wp,
    const float* __restrict__ bp, float* __restrict__ fglob) {
  __shared__ __align__(16) char smem[49152];
  const int bid = blockIdx.x;
  if (bid < 192) {
    const bool first = bid < 96;
    const GemmJob& j = first ? jwo0 : jwo1;
    const int orig = first ? bid : bid - 96;
    const int b2 = xcd_remap(orig, 96);
    gemm_body<false, true>(j, b2 % j.colTiles, b2 / j.colTiles, threadIdx.x, smem,
                           timg, ftok, stok);
  } else if (bid < 576) {
    const int idx = bid - 192;
    text_gat_body(smem, idx % 12, idx / 12, qa_bf + 768, 1536, text_adj, at, tgf);
  } else if (bid < 960) {
    const int idx = bid - 576;
    image_gat_body(smem, idx % 12, idx / 12, whi, ldw_i, ai, image_adj, igf);
  } else {
    const int idx = bid - 960;
    fglob_body(smem, idx % 12, idx / 12, clip_t, Wp, bp, fglob);
  }
}

// ---------------- Xc = [f_token; tgf; fglob] @ c1w : grid (6, 96) ----------------
__global__ __launch_bounds__(256) void xc1_kernel(
    const float* __restrict__ ftok, const float* __restrict__ tgf,
    const float* __restrict__ fglob, const float* __restrict__ c1w,
    float* __restrict__ Xc) {
  const int jt = blockIdx.x;
  const int r = blockIdx.y;
  const int b = r & 31, which = r >> 5;
  const float* src = (which == 0 ? ftok : which == 1 ? tgf : fglob) + (size_t)b * D;
  const int j = threadIdx.x & 63, kc = threadIdx.x >> 6;
  const int col = jt * 64 + j;
  const float* cw = c1w + (size_t)(kc * 192) * 384 + col;
  const float* sk = src + kc * 192;
  float s0 = 0.f, s1 = 0.f, s2 = 0.f, s3 = 0.f;
#pragma unroll 12
  for (int k = 0; k < 192; k += 4) {
    s0 += sk[k]     * cw[(size_t)k * 384];
    s1 += sk[k + 1] * cw[(size_t)(k + 1) * 384];
    s2 += sk[k + 2] * cw[(size_t)(k + 2) * 384];
    s3 += sk[k + 3] * cw[(size_t)(k + 3) * 384];
  }
  __shared__ float red[4][64];
  red[kc][j] = (s0 + s1) + (s2 + s3);
  __syncthreads();
  if (kc == 0)
    Xc[(size_t)r * 384 + col] = red[0][j] + red[1][j] + red[2][j] + red[3][j];
}

// ---------------- final fusion kernel: one block per b ----------------
__device__ __forceinline__ float block_sum(float v, float* red4) {
  v = wave_sum(v);
  __syncthreads();
  if ((threadIdx.x & 63) == 0) red4[threadIdx.x >> 6] = v;
  __syncthreads();
  return red4[0] + red4[1] + red4[2] + red4[3];
}

__global__ __launch_bounds__(256) void final_kernel(
    const float* __restrict__ tgf, const float* __restrict__ igf,
    const float* __restrict__ clip_t, const float* __restrict__ clip_i,
    const float* __restrict__ logit_scale, const float* __restrict__ s_token,
    const float* __restrict__ Xc,
    const float* __restrict__ f1w, const float* __restrict__ f1b,
    const float* __restrict__ f2w, const float* __restrict__ f2b,
    const float* __restrict__ c1b,
    const float* __restrict__ c2w, const float* __restrict__ c2b,
    float* __restrict__ out) {
  const int b = blockIdx.x, tid = threadIdx.x;
  __shared__ float red[4];
  __shared__ float sres[4];
  __shared__ float hid[384];

  float d0 = 0.f, d1 = 0.f, d2 = 0.f;
  for (int i = tid; i < D; i += 256) {
    float x = tgf[b * D + i], y = igf[b * D + i];
    d0 += x * y; d1 += x * x; d2 += y * y;
  }
  float dot_ti = block_sum(d0, red);
  float n_t = sqrtf(block_sum(d1, red));
  float n_i = sqrtf(block_sum(d2, red));
  float s_phrase = dot_ti / (fmaxf(n_t, 1e-8f) * fmaxf(n_i, 1e-8f));

  float c0 = 0.f, c1 = 0.f, c2 = 0.f;
  for (int i = tid; i < 512; i += 256) {
    float x = clip_t[b * 512 + i], y = clip_i[b * 512 + i];
    c0 += x * y; c1 += x * x; c2 += y * y;
  }
  float dc = block_sum(c0, red);
  float nt2 = sqrtf(block_sum(c1, red));
  float ni2 = sqrtf(block_sum(c2, red));
  float s_global = expf(logit_scale[0]) * dc / (fmaxf(nt2, 1e-8f) * fmaxf(ni2, 1e-8f));

  if (tid == 0) {
    float s3[3] = { s_token[b], s_phrase, s_global };
    float h1[16];
    for (int j = 0; j < 16; ++j) {
      float a = f1b[j];
      for (int i2 = 0; i2 < 3; ++i2) a += s3[i2] * f1w[i2 * 16 + j];
      h1[j] = 0.5f * a * (1.0f + erff(a * 0.70710678118654752f));
    }
    for (int j = 0; j < 3; ++j) {
      float a = f2b[j];
      for (int i2 = 0; i2 < 16; ++i2) a += h1[i2] * f2w[i2 * 3 + j];
      sres[j] = 1.0f / (1.0f + expf(-a));
    }
  }
  __syncthreads();
  const float w0 = sres[0], w1 = sres[1], w2 = sres[2];

  for (int j = tid; j < 384; j += 256) {
    const float a = w0 * Xc[(size_t)b * 384 + j] +
                    w1 * Xc[(size_t)(32 + b) * 384 + j] +
                    w2 * Xc[(size_t)(64 + b) * 384 + j] + c1b[j];
    hid[j] = fmaxf(a, 0.0f);
  }
  __syncthreads();

  float p0 = 0.f, p1 = 0.f;
  for (int k2 = tid; k2 < 384; k2 += 256) {
    p0 += hid[k2] * c2w[k2 * 2 + 0];
    p1 += hid[k2] * c2w[k2 * 2 + 1];
  }
  p0 = block_sum(p0, red);
  p1 = block_sum(p1, red);
  if (tid == 0) {
    out[b * 2 + 0] = p0 + c2b[0];
    out[b * 2 + 1] = p1 + c2b[1];
  }
}

// ---------------- launch ----------------
extern "C" void kernel_launch(void* const* d_in, const int* in_sizes, int n_in,
                              void* d_out, int out_size, void* d_ws, size_t ws_size,
                              hipStream_t stream) {
  const float* text   = (const float*)d_in[0];
  const float* img    = (const float*)d_in[1];
  const float* clip_t = (const float*)d_in[2];
  const float* clip_i = (const float*)d_in[3];
  const float* lscale = (const float*)d_in[4];
  const float* wq = (const float*)d_in[5];
  const float* bq = (const float*)d_in[6];
  const float* wk = (const float*)d_in[7];
  const float* bk = (const float*)d_in[8];
  const float* wv = (const float*)d_in[9];
  const float* bv = (const float*)d_in[10];
  const float* wo = (const float*)d_in[11];
  const float* bo = (const float*)d_in[12];
  const float* Wt = (const float*)d_in[13];
  const float* at = (const float*)d_in[14];
  const float* Wi = (const float*)d_in[15];
  const float* ai = (const float*)d_in[16];
  const float* Wp = (const float*)d_in[17];
  const float* bp = (const float*)d_in[18];
  const float* f1w = (const float*)d_in[19];
  const float* f1b = (const float*)d_in[20];
  const float* f2w = (const float*)d_in[21];
  const float* f2b = (const float*)d_in[22];
  const float* c1w = (const float*)d_in[23];
  const float* c1b = (const float*)d_in[24];
  const float* c2w = (const float*)d_in[25];
  const float* c2b = (const float*)d_in[26];
  const int* text_adj  = (const int*)d_in[27];
  const int* image_adj = (const int*)d_in[28];
  float* out = (float*)d_out;

  const size_t nTD = (size_t)B * T * D;   // 1,572,864
  const size_t nPD = (size_t)B * P * D;   // 4,816,896
  const size_t nWW = (size_t)D * D;       // 589,824

  // ---- workspace layout (no aliasing) ----
  float* fbuf = (float*)d_ws;
  size_t o = 0;
  float* ftok    = fbuf + o; o += (size_t)B * D;
  float* stok    = fbuf + o; o += 32;
  float* tgf     = fbuf + o; o += (size_t)B * D;
  float* igf     = fbuf + o; o += (size_t)B * D;
  float* fglob   = fbuf + o; o += (size_t)B * D;
  float* bcat_t  = fbuf + o; o += 1536;
  float* bcat_i3 = fbuf + o; o += 2304;
  float* Xc      = fbuf + o; o += (size_t)96 * 384;
  unsigned short* sbuf = (unsigned short*)(fbuf + o);
  size_t so = 0;
  unsigned short* kvw_bf    = sbuf + so; so += 3 * nPD;  // [B*P][2304] bf16: k|v|Wh_i
  unsigned short* qa_bf     = sbuf + so; so += 2 * nTD;  // [B*T][1536] bf16: q|Wh_t
  unsigned short* text_bf   = sbuf + so; so += nTD;
  unsigned short* img_bf    = sbuf + so; so += nPD;
  unsigned short* att_bf    = sbuf + so; so += nTD;
  unsigned short* wcat_txt  = sbuf + so; so += 2 * nWW;  // wq^T | Wt^T
  unsigned short* wcat_img3 = sbuf + so; so += 3 * nWW;  // wk^T | wv^T | Wi^T
  unsigned short* wo_t      = sbuf + so; so += nWW;

  // ---- fused prep: weight cast-transposes + biases + casts + ftok/stok zero ----
  WPack wp;
  wp.src[0] = wq; wp.dst[0] = wcat_txt;
  wp.src[1] = Wt; wp.dst[1] = wcat_txt + nWW;
  wp.src[2] = wk; wp.dst[2] = wcat_img3;
  wp.src[3] = wv; wp.dst[3] = wcat_img3 + nWW;
  wp.src[4] = Wi; wp.dst[4] = wcat_img3 + 2 * nWW;
  wp.src[5] = wo; wp.dst[5] = wo_t;
  {
    const int n40 = (int)(nTD / 4), n41 = (int)(nPD / 4);
    prep_kernel<<<9792, 256, 0, stream>>>(wp, text, text_bf, n40, img, img_bf, n41,
                                          bq, bk, bv, bcat_t, bcat_i3, stok, ftok);
  }

  const int MT = B * T;   // 2048
  const int MP = B * P;   // 6272

  // ---- fused projections (bf16 C output): one dual launch ----
  GemmJob jimg;  // kvw_bf = img @ [wk|wv|Wi] + [bk,bv,0]
  jimg.A = img_bf; jimg.Bt = wcat_img3; jimg.bias = bcat_i3; jimg.C = kvw_bf;
  jimg.N = 2304; jimg.K = D; jimg.lda = D; jimg.ldb = D; jimg.colTiles = 2304 / 128;
  GemmJob jtxt;  // qa_bf = text @ [wq|Wt] + [bq,0]
  jtxt.A = text_bf; jtxt.Bt = wcat_txt; jtxt.bias = bcat_t; jtxt.C = qa_bf;
  jtxt.N = 1536; jtxt.K = D; jtxt.lda = D; jtxt.ldb = D; jtxt.colTiles = 1536 / 128;
  const int splitBlocks = (2304 / 128) * (MP / 128);                // 882
  const int totalBlocks = splitBlocks + (1536 / 128) * (MT / 128);  // 882 + 192
  gemm_mfma_dual_bf16<<<totalBlocks, 256, 0, stream>>>(jimg, jtxt, splitBlocks, totalBlocks);

  // ---- attention (feeds the wo GEMM in combo) ----
  attn_kernel<<<dim3(H, B), 256, 0, stream>>>(qa_bf, kvw_bf, att_bf);

  // ---- combo: wo-GEMM split-K x2 (token-fused) + text GAT + image GAT + fglob ----
  GemmJob jwo0;  // partial0 = att[:, :384] @ wo_t[:, :384]^T + bo  -> token atomics
  jwo0.A = att_bf; jwo0.Bt = wo_t; jwo0.bias = bo; jwo0.C = nullptr;
  jwo0.N = D; jwo0.K = 384; jwo0.lda = D; jwo0.ldb = D; jwo0.colTiles = D / 128;
  GemmJob jwo1;  // partial1 = att[:, 384:] @ wo_t[:, 384:]^T       -> token atomics
  jwo1.A = att_bf + 384; jwo1.Bt = wo_t + 384; jwo1.bias = nullptr; jwo1.C = nullptr;
  jwo1.N = D; jwo1.K = 384; jwo1.lda = D; jwo1.ldb = D; jwo1.colTiles = D / 128;
  const unsigned short* whi_bf = kvw_bf + 1536;
  combo_kernel<<<1344, 256, 0, stream>>>(
      jwo0, jwo1, img, ftok, stok,
      qa_bf, text_adj, at, tgf,
      whi_bf, 2304, ai, image_adj, igf,
      clip_t, Wp, bp, fglob);

  xc1_kernel<<<dim3(6, 96), 256, 0, stream>>>(ftok, tgf, fglob, c1w, Xc);
  final_kernel<<<B, 256, 0, stream>>>(tgf, igf, clip_t, clip_i, lscale, stok, Xc,
                                      f1w, f1b, f2w, f2b, c1b, c2w, c2b, out);
}